// Round 12
// baseline (486.005 us; speedup 1.0000x reference)
//
#include <hip/hip_runtime.h>
#include <math.h>

#define B_ 8
#define T_ 12
#define N_ 200
#define R_ 1600    // B*N
#define NN_ 40000  // N*N

__device__ __forceinline__ float sigm(float v) { return 1.f / (1.f + expf(-v)); }

// ======== Phase A: dy-GRU chain + P/Q projections ====
// R9-proven: weights TRANSPOSED in LDS, all inner loops float4 LDS reads.
__global__ void __launch_bounds__(256) k_dyall(
        const float* __restrict__ x,  const float* __restrict__ nf,
        const float* __restrict__ Ws2d, const float* __restrict__ bs2d,
        const float* __restrict__ Wrz,  const float* __restrict__ brz,
        const float* __restrict__ Wh,   const float* __restrict__ bh,
        const float* __restrict__ Wc2,  const float* __restrict__ Wm2,
        const float* __restrict__ bc2,  const float* __restrict__ bm2,
        float* __restrict__ Pc, float* __restrict__ Qc,
        float* __restrict__ Pm, float* __restrict__ Qm,
        float* __restrict__ state) {
    __shared__ alignas(16) float sWs2d[64 * 32];
    __shared__ alignas(16) float sWrzT[64][36];   // [o][i], i 0..32, pad->36
    __shared__ alignas(16) float sWhT[32][36];    // [k][i]
    __shared__ alignas(16) float sWc2T[32][68];   // [k][r], r 0..63, pad->68
    __shared__ alignas(16) float sWm2T[32][68];
    __shared__ float sbrz[64], sbh[32], sbs2d[32], sbc2[32], sbm2[32];
    __shared__ alignas(16) float nfs[4][64], dy[4][32], rz[4][64], s4[4][32];
    __shared__ alignas(16) float in1[4][36], in2[4][36];
    int bk = blockIdx.x, tid = threadIdx.x;
    int w = tid >> 6, o = tid & 63;
    int row = bk * 4 + w, b = row / N_, n = row % N_;
    state[bk * 256 + tid] = 0.f;
    for (int idx = tid; idx < 2048; idx += 256) sWs2d[idx] = Ws2d[idx];
    for (int idx = tid; idx < 2304; idx += 256) {
        int oo = idx / 36, ii = idx % 36;
        sWrzT[oo][ii] = (ii < 33) ? Wrz[ii * 64 + oo] : 0.f;
    }
    for (int idx = tid; idx < 1152; idx += 256) {
        int kk = idx / 36, ii = idx % 36;
        sWhT[kk][ii] = (ii < 33) ? Wh[ii * 32 + kk] : 0.f;
    }
    for (int idx = tid; idx < 2176; idx += 256) {
        int kk = idx / 68, rr = idx % 68;
        float vc = (rr < 64) ? Wc2[rr * 32 + kk] : 0.f;
        float vm = (rr < 64) ? Wm2[rr * 32 + kk] : 0.f;
        sWc2T[kk][rr] = vc; sWm2T[kk][rr] = vm;
    }
    if (tid < 144) { ((float*)in1)[tid] = 0.f; ((float*)in2)[tid] = 0.f; }
    if (tid < 64) sbrz[tid] = brz[tid];
    if (tid < 32) { sbh[tid] = bh[tid]; sbs2d[tid] = bs2d[tid];
                    sbc2[tid] = bc2[tid]; sbm2[tid] = bm2[tid]; }
    nfs[w][o] = nf[n * 64 + o];
    __syncthreads();
    if (o < 32) {
        float acc = sbs2d[o];
        #pragma unroll 8
        for (int i = 0; i < 64; ++i) acc += nfs[w][i] * sWs2d[i * 32 + o];
        dy[w][o] = acc;
    }
    __syncthreads();
    for (int t = 0; t < T_; ++t) {
        if (o == 0) { float v = x[((b * T_ + t) * N_ + n) * 2]; in1[w][0] = v; in2[w][0] = v; }
        if (o < 32) in1[w][o + 1] = dy[w][o];
        __syncthreads();
        float acc = sbrz[o];
        #pragma unroll
        for (int ig = 0; ig < 9; ++ig) {
            float4 w4 = *(const float4*)&sWrzT[o][4 * ig];
            float4 f4 = *(const float4*)&in1[w][4 * ig];
            acc += f4.x * w4.x + f4.y * w4.y + f4.z * w4.z + f4.w * w4.w;
        }
        rz[w][o] = sigm(acc);
        __syncthreads();
        if (o < 32) in2[w][o + 1] = rz[w][o] * dy[w][o];
        __syncthreads();
        if (o < 32) {
            float h = sbh[o];
            #pragma unroll
            for (int ig = 0; ig < 9; ++ig) {
                float4 w4 = *(const float4*)&sWhT[o][4 * ig];
                float4 f4 = *(const float4*)&in2[w][4 * ig];
                h += f4.x * w4.x + f4.y * w4.y + f4.z * w4.z + f4.w * w4.w;
            }
            h = tanhf(h);
            float z = rz[w][32 + o];
            float nd = z * dy[w][o] + (1.f - z) * h;
            dy[w][o] = nd;
            s4[w][o] = nd > 0.f ? nd : 0.f;
        }
        __syncthreads();
        size_t base = ((size_t)t * R_ + row) * 32;
        for (int idx = o; idx < 128; idx += 64) {
            int mat = idx >> 5, k = idx & 31;
            const float* WT = (mat < 2) ? &sWc2T[k][0] : &sWm2T[k][0];
            int rb = (mat & 1) ? 32 : 0;
            float a = (mat == 0) ? sbc2[k] : (mat == 2) ? sbm2[k] : 0.f;
            #pragma unroll
            for (int ig = 0; ig < 8; ++ig) {
                float4 w4 = *(const float4*)&WT[rb + 4 * ig];
                float4 f4 = *(const float4*)&s4[w][4 * ig];
                a += f4.x * w4.x + f4.y * w4.y + f4.z * w4.z + f4.w * w4.w;
            }
            ((mat == 0) ? Pc : (mat == 1) ? Qc : (mat == 2) ? Pm : Qm)[base + k] = a;
        }
        __syncthreads();
    }
}

// ======== Phase B: adjacency — R10-proven 16x16 tile, W in registers ====
__global__ void __launch_bounds__(256) k_pairall(
        const float* __restrict__ Pc, const float* __restrict__ Qc,
        const float* __restrict__ Pm, const float* __restrict__ Qm,
        const float* __restrict__ Wc1, const float* __restrict__ bc1,
        const float* __restrict__ Wm1, const float* __restrict__ bm1,
        float* __restrict__ out) {
    __shared__ float sPc[16][36], sQc[16][36], sPm[16][36], sQm[16][36];
    int z = blockIdx.z;            // t*8 + b
    int i0 = blockIdx.x * 16, j0 = blockIdx.y * 16;
    int tid = threadIdx.y * 16 + threadIdx.x;
    size_t tb = (size_t)z * N_;
    for (int l = tid; l < 128; l += 256) {   // 16 rows x 8 float4
        int r = l >> 3, q = l & 7;
        int gi = i0 + r, gj = j0 + r;
        float4 z4 = make_float4(0.f, 0.f, 0.f, 0.f);
        *(float4*)&sPc[r][4 * q] = (gi < N_) ? *(const float4*)&Pc[(tb + gi) * 32 + 4 * q] : z4;
        *(float4*)&sPm[r][4 * q] = (gi < N_) ? *(const float4*)&Pm[(tb + gi) * 32 + 4 * q] : z4;
        *(float4*)&sQc[r][4 * q] = (gj < N_) ? *(const float4*)&Qc[(tb + gj) * 32 + 4 * q] : z4;
        *(float4*)&sQm[r][4 * q] = (gj < N_) ? *(const float4*)&Qm[(tb + gj) * 32 + 4 * q] : z4;
    }
    float4 wc[8], wm[8];
    #pragma unroll
    for (int kg = 0; kg < 8; ++kg) {
        wc[kg] = *(const float4*)&Wc1[4 * kg];
        wm[kg] = *(const float4*)&Wm1[4 * kg];
    }
    __syncthreads();
    int i = i0 + threadIdx.y, j = j0 + threadIdx.x;
    if (i >= N_ || j >= N_) return;
    int ty = threadIdx.y, tx = threadIdx.x;
    float g0 = 0.f, g1 = 0.f, m0 = 0.f, m1 = 0.f;
    #pragma unroll
    for (int kg = 0; kg < 8; ++kg) {
        float4 pc = *(const float4*)&sPc[ty][4 * kg];
        float4 qc = *(const float4*)&sQc[tx][4 * kg];
        float4 w4 = wc[kg];
        g0 += fmaxf(pc.x + qc.x, 0.f) * w4.x + fmaxf(pc.y + qc.y, 0.f) * w4.y;
        g1 += fmaxf(pc.z + qc.z, 0.f) * w4.z + fmaxf(pc.w + qc.w, 0.f) * w4.w;
        float4 pm = *(const float4*)&sPm[ty][4 * kg];
        float4 qm = *(const float4*)&sQm[tx][4 * kg];
        float4 v4 = wm[kg];
        m0 += fmaxf(pm.x + qm.x, 0.f) * v4.x + fmaxf(pm.y + qm.y, 0.f) * v4.y;
        m1 += fmaxf(pm.z + qm.z, 0.f) * v4.z + fmaxf(pm.w + qm.w, 0.f) * v4.w;
    }
    float g = g0 + g1 + bc1[0];
    float m = m0 + m1 + bm1[0];
    out[R_ + (((size_t)z * N_ + i) * N_ + j)] = g * sigm(m);
}

// ======== A2 = A @ A — R1-proven: 128x64 tile, 256 thr, 8x4 micro, BK=32 ==
__global__ void __launch_bounds__(256) k_a2(
        const float* __restrict__ Abase, float* __restrict__ Cbase, int nmat) {
    __shared__ float Ast[32][132];   // [k][i] transposed
    __shared__ float Bs[32][68];     // [k][j]
    int bx = blockIdx.x;
    int z = bx % nmat, tl = bx / nmat;      // z fastest => XCD-local matrices
    int i0 = (tl >> 2) * 128, j0 = (tl & 3) * 64;
    const float* Az = Abase + (size_t)z * NN_;
    float* Cz = Cbase + (size_t)z * NN_;
    int tid = threadIdx.x;
    int tx = tid & 15, ty = tid >> 4;       // tx: 4-col group, ty: 8-row group
    float acc[8][4] = {};
    for (int k0 = 0; k0 < 200; k0 += 32) {
        {
            int i = tid >> 1;                 // 0..127
            int kb = (tid & 1) * 16;          // 0 or 16
            int gi = i0 + i;
            #pragma unroll
            for (int q = 0; q < 4; ++q) {
                int k = kb + q * 4;
                int gk = k0 + k;
                float4 v = make_float4(0.f, 0.f, 0.f, 0.f);
                if (gi < N_) {
                    if (gk + 3 < N_) v = *(const float4*)&Az[gi * N_ + gk];
                    else {
                        float t0 = (gk + 0 < N_) ? Az[gi * N_ + gk + 0] : 0.f;
                        float t1 = (gk + 1 < N_) ? Az[gi * N_ + gk + 1] : 0.f;
                        float t2 = (gk + 2 < N_) ? Az[gi * N_ + gk + 2] : 0.f;
                        float t3 = (gk + 3 < N_) ? Az[gi * N_ + gk + 3] : 0.f;
                        v = make_float4(t0, t1, t2, t3);
                    }
                }
                Ast[k + 0][i] = v.x; Ast[k + 1][i] = v.y;
                Ast[k + 2][i] = v.z; Ast[k + 3][i] = v.w;
            }
        }
        {
            #pragma unroll
            for (int q = 0; q < 2; ++q) {
                int id = tid + 256 * q;       // 0..511
                int k = id >> 4, jq = (id & 15) * 4;
                int gk = k0 + k, gj = j0 + jq;
                float4 v = make_float4(0.f, 0.f, 0.f, 0.f);
                if (gk < N_) {
                    if (gj + 3 < N_) v = *(const float4*)&Az[gk * N_ + gj];
                    else {
                        float t0 = (gj + 0 < N_) ? Az[gk * N_ + gj + 0] : 0.f;
                        float t1 = (gj + 1 < N_) ? Az[gk * N_ + gj + 1] : 0.f;
                        float t2 = (gj + 2 < N_) ? Az[gk * N_ + gj + 2] : 0.f;
                        float t3 = (gj + 3 < N_) ? Az[gk * N_ + gj + 3] : 0.f;
                        v = make_float4(t0, t1, t2, t3);
                    }
                }
                *(float4*)&Bs[k][jq] = v;
            }
        }
        __syncthreads();
        #pragma unroll 8
        for (int k = 0; k < 32; ++k) {
            float4 a0 = *(const float4*)&Ast[k][ty * 8];
            float4 a1 = *(const float4*)&Ast[k][ty * 8 + 4];
            float4 bv = *(const float4*)&Bs[k][tx * 4];
            acc[0][0] += a0.x * bv.x; acc[0][1] += a0.x * bv.y; acc[0][2] += a0.x * bv.z; acc[0][3] += a0.x * bv.w;
            acc[1][0] += a0.y * bv.x; acc[1][1] += a0.y * bv.y; acc[1][2] += a0.y * bv.z; acc[1][3] += a0.y * bv.w;
            acc[2][0] += a0.z * bv.x; acc[2][1] += a0.z * bv.y; acc[2][2] += a0.z * bv.z; acc[2][3] += a0.z * bv.w;
            acc[3][0] += a0.w * bv.x; acc[3][1] += a0.w * bv.y; acc[3][2] += a0.w * bv.z; acc[3][3] += a0.w * bv.w;
            acc[4][0] += a1.x * bv.x; acc[4][1] += a1.x * bv.y; acc[4][2] += a1.x * bv.z; acc[4][3] += a1.x * bv.w;
            acc[5][0] += a1.y * bv.x; acc[5][1] += a1.y * bv.y; acc[5][2] += a1.y * bv.z; acc[5][3] += a1.y * bv.w;
            acc[6][0] += a1.z * bv.x; acc[6][1] += a1.z * bv.y; acc[6][2] += a1.z * bv.z; acc[6][3] += a1.z * bv.w;
            acc[7][0] += a1.w * bv.x; acc[7][1] += a1.w * bv.y; acc[7][2] += a1.w * bv.z; acc[7][3] += a1.w * bv.w;
        }
        __syncthreads();
    }
    #pragma unroll
    for (int r = 0; r < 8; ++r) {
        int gi = i0 + ty * 8 + r;
        if (gi >= N_) continue;
        int gj = j0 + tx * 4;
        if (gj + 3 < N_) {
            *(float4*)&Cz[gi * N_ + gj] = make_float4(acc[r][0], acc[r][1], acc[r][2], acc[r][3]);
        } else {
            #pragma unroll
            for (int e = 0; e < 4; ++e) if (gj + e < N_) Cz[gi * N_ + gj + e] = acc[r][e];
        }
    }
}

// ======== xt-hops: xh[zl][i][4] = {A@x0, A@x1, A2@x0, A2@x1} ========
__global__ void __launch_bounds__(256) k_xh(
        const float* __restrict__ Abase, const float* __restrict__ A2base,
        const float* __restrict__ x, int z0, float* __restrict__ xh) {
    __shared__ float xtl[400];
    int zl = blockIdx.x, tid = threadIdx.x;
    int z = z0 + zl, t = z >> 3, b = z & 7;
    int w = tid >> 6, l = tid & 63;
    const float* xb = x + ((size_t)(b * T_ + t)) * N_ * 2;
    for (int idx = tid; idx < 400; idx += 256) xtl[idx] = xb[idx];
    __syncthreads();
    for (int it = 0; it < 50; ++it) {
        int i = it * 4 + w;
        float p0 = 0.f, p1 = 0.f, p2 = 0.f, p3 = 0.f;
        if (l < 50) {
            float4 a4 = *(const float4*)(Abase + (size_t)zl * NN_ + i * 200 + 4 * l);
            float4 c4 = *(const float4*)(A2base + (size_t)zl * NN_ + i * 200 + 4 * l);
            #pragma unroll
            for (int q = 0; q < 4; ++q) {
                float av = (&a4.x)[q], cv = (&c4.x)[q];
                float x0 = xtl[(4 * l + q) * 2], x1 = xtl[(4 * l + q) * 2 + 1];
                p0 += av * x0; p1 += av * x1; p2 += cv * x0; p3 += cv * x1;
            }
        }
        #pragma unroll
        for (int off = 32; off > 0; off >>= 1) {
            p0 += __shfl_down(p0, off); p1 += __shfl_down(p1, off);
            p2 += __shfl_down(p2, off); p3 += __shfl_down(p3, off);
        }
        if (l == 0) *(float4*)(xh + ((size_t)zl * N_ + i) * 4) = make_float4(p0, p1, p2, p3);
    }
}

// ======== K1: 1 row/block, 1600 blocks (double co-residency vs R11).
// Waves 0-1: hop (wave h = j-half, both A and A2 for the row).
// Waves 2-3: gate-part1 (k<68) concurrent. Then all: gate-part2, reduce.
__global__ void __launch_bounds__(256) k_ru1(
        const float* __restrict__ At, const float* __restrict__ A2t,
        const float* __restrict__ xht,
        const float* __restrict__ x, int t, const float* __restrict__ state,
        const float* __restrict__ Wru, const float* __restrict__ bru,
        float* __restrict__ rs, float* __restrict__ ub) {
    __shared__ float a1s[200], c1s[200];
    __shared__ float hpA[2][64], hpC[2][64];   // [h][c]
    __shared__ float feat[200];
    __shared__ float gp[12][128];              // part1: 0..3, part2: 4..11
    int bx = blockIdx.x;
    int b = bx & 7, i = bx >> 3;               // b == XCD -> state L2-local
    int tid = threadIdx.x;
    const float* F = state + (size_t)b * (N_ * 64);
    {   // stage: A/A2 row, F row -> feat[2..66), x -> [0..2), xh
        const float4* Ar = (const float4*)(At + ((size_t)b * N_ + i) * 200);
        const float4* Cr = (const float4*)(A2t + ((size_t)b * N_ + i) * 200);
        if (tid < 50) { ((float4*)a1s)[tid] = Ar[tid]; ((float4*)c1s)[tid] = Cr[tid]; }
        if (tid >= 64 && tid < 96) {
            int l = tid - 64;
            *(float2*)&feat[2 + 2 * l] = *(const float2*)&F[(size_t)i * 64 + 2 * l];
        }
        if (tid >= 96 && tid < 98) {
            int l = tid - 96;
            feat[l] = x[((size_t)(b * T_ + t) * N_ + i) * 2 + l];
        }
        if (tid >= 100 && tid < 104) {
            int q = tid - 100;
            feat[(q < 2) ? (66 + q) : (132 + q - 2)] = xht[((size_t)b * N_ + i) * 4 + q];
        }
    }
    __syncthreads();
    int w = tid >> 6, lane = tid & 63;
    if (w < 2) {   // hop: wave h owns j-half, computes A and A2
        int h = w;
        int cg = lane & 15, jq = lane >> 4;
        const float* ap = a1s + h * 100;
        const float* cp = c1s + h * 100;
        const float* Fb = F + (size_t)(h * 100) * 64 + 4 * cg;
        float4 aA = make_float4(0.f, 0.f, 0.f, 0.f), aC = aA;
        #pragma unroll 5
        for (int m = 0; m < 25; ++m) {
            int j = jq + 4 * m;
            float4 f4 = *(const float4*)&Fb[(size_t)j * 64];
            float a = ap[j], c = cp[j];
            aA.x += a * f4.x; aA.y += a * f4.y; aA.z += a * f4.z; aA.w += a * f4.w;
            aC.x += c * f4.x; aC.y += c * f4.y; aC.z += c * f4.z; aC.w += c * f4.w;
        }
        #pragma unroll
        for (int off = 16; off <= 32; off <<= 1) {
            aA.x += __shfl_xor(aA.x, off); aA.y += __shfl_xor(aA.y, off);
            aA.z += __shfl_xor(aA.z, off); aA.w += __shfl_xor(aA.w, off);
            aC.x += __shfl_xor(aC.x, off); aC.y += __shfl_xor(aC.y, off);
            aC.z += __shfl_xor(aC.z, off); aC.w += __shfl_xor(aC.w, off);
        }
        if (lane < 16) {
            *(float4*)&hpA[h][4 * cg] = aA;
            *(float4*)&hpC[h][4 * cg] = aC;
        }
    } else {   // gate-part1: k in [0,68)
        int l = tid - 128;            // 0..127
        int cq = l & 31, kh = l >> 5; // kh 0..3
        int k0 = 17 * kh, kend = (k0 + 17 < 68) ? (k0 + 17) : 68;
        float4 s0 = make_float4(0.f, 0.f, 0.f, 0.f);
        for (int k = k0; k < kend; ++k) {
            float4 w4 = *(const float4*)&Wru[(size_t)k * 128 + 4 * cq];
            float f0 = feat[k];
            s0.x += f0 * w4.x; s0.y += f0 * w4.y; s0.z += f0 * w4.z; s0.w += f0 * w4.w;
        }
        *(float4*)&gp[kh][4 * cq] = s0;
    }
    __syncthreads();
    if (tid < 128) {   // combine j-halves into feat[68..132), [134..198)
        int mt = tid >> 6, c = tid & 63;
        float v = mt ? (hpC[0][c] + hpC[1][c]) : (hpA[0][c] + hpA[1][c]);
        feat[(mt ? 134 : 68) + c] = v;
    }
    __syncthreads();
    {   // gate-part2: k in [68,198), 8 splits of 17 (last 11)
        int cq = tid & 31, kh = tid >> 5;
        int k0 = 68 + 17 * kh, kend = (k0 + 17 < 198) ? (k0 + 17) : 198;
        float4 s0 = make_float4(0.f, 0.f, 0.f, 0.f);
        for (int k = k0; k < kend; ++k) {
            float4 w4 = *(const float4*)&Wru[(size_t)k * 128 + 4 * cq];
            float f0 = feat[k];
            s0.x += f0 * w4.x; s0.y += f0 * w4.y; s0.z += f0 * w4.z; s0.w += f0 * w4.w;
        }
        *(float4*)&gp[4 + kh][4 * cq] = s0;
    }
    __syncthreads();
    if (tid < 128) {   // reduce + activation + store
        int c = tid;
        float a = bru[c];
        #pragma unroll
        for (int h = 0; h < 12; ++h) a += gp[h][c];
        float v = sigm(a);
        size_t go = (size_t)b * N_ + i;
        if (c < 64) rs[go * 64 + c] = v * feat[2 + c];
        else        ub[go * 64 + (c - 64)] = v;
    }
}

// ======== K2: same 1-row structure, 64-col gate ========
__global__ void __launch_bounds__(256) k_cand1(
        const float* __restrict__ At, const float* __restrict__ A2t,
        const float* __restrict__ xht,
        const float* __restrict__ x, int t, const float* __restrict__ rsin,
        const float* __restrict__ Wcd, const float* __restrict__ bcd,
        const float* __restrict__ ub, float* __restrict__ state) {
    __shared__ float a1s[200], c1s[200];
    __shared__ float hpA[2][64], hpC[2][64];
    __shared__ float feat[200];
    __shared__ float gp[24][64];               // part1: 0..7, part2: 8..23
    int bx = blockIdx.x;
    int b = bx & 7, i = bx >> 3;
    int tid = threadIdx.x;
    const float* F = rsin + (size_t)b * (N_ * 64);
    {
        const float4* Ar = (const float4*)(At + ((size_t)b * N_ + i) * 200);
        const float4* Cr = (const float4*)(A2t + ((size_t)b * N_ + i) * 200);
        if (tid < 50) { ((float4*)a1s)[tid] = Ar[tid]; ((float4*)c1s)[tid] = Cr[tid]; }
        if (tid >= 64 && tid < 96) {
            int l = tid - 64;
            *(float2*)&feat[2 + 2 * l] = *(const float2*)&F[(size_t)i * 64 + 2 * l];
        }
        if (tid >= 96 && tid < 98) {
            int l = tid - 96;
            feat[l] = x[((size_t)(b * T_ + t) * N_ + i) * 2 + l];
        }
        if (tid >= 100 && tid < 104) {
            int q = tid - 100;
            feat[(q < 2) ? (66 + q) : (132 + q - 2)] = xht[((size_t)b * N_ + i) * 4 + q];
        }
    }
    __syncthreads();
    int w = tid >> 6, lane = tid & 63;
    if (w < 2) {   // hop over rs
        int h = w;
        int cg = lane & 15, jq = lane >> 4;
        const float* ap = a1s + h * 100;
        const float* cp = c1s + h * 100;
        const float* Fb = F + (size_t)(h * 100) * 64 + 4 * cg;
        float4 aA = make_float4(0.f, 0.f, 0.f, 0.f), aC = aA;
        #pragma unroll 5
        for (int m = 0; m < 25; ++m) {
            int j = jq + 4 * m;
            float4 f4 = *(const float4*)&Fb[(size_t)j * 64];
            float a = ap[j], c = cp[j];
            aA.x += a * f4.x; aA.y += a * f4.y; aA.z += a * f4.z; aA.w += a * f4.w;
            aC.x += c * f4.x; aC.y += c * f4.y; aC.z += c * f4.z; aC.w += c * f4.w;
        }
        #pragma unroll
        for (int off = 16; off <= 32; off <<= 1) {
            aA.x += __shfl_xor(aA.x, off); aA.y += __shfl_xor(aA.y, off);
            aA.z += __shfl_xor(aA.z, off); aA.w += __shfl_xor(aA.w, off);
            aC.x += __shfl_xor(aC.x, off); aC.y += __shfl_xor(aC.y, off);
            aC.z += __shfl_xor(aC.z, off); aC.w += __shfl_xor(aC.w, off);
        }
        if (lane < 16) {
            *(float4*)&hpA[h][4 * cg] = aA;
            *(float4*)&hpC[h][4 * cg] = aC;
        }
    } else {   // gate-part1: k in [0,68), 8 splits of 9
        int l = tid - 128;            // 0..127
        int cq = l & 15, kh = l >> 4; // kh 0..7
        int k0 = 9 * kh, kend = (k0 + 9 < 68) ? (k0 + 9) : 68;
        float4 s0 = make_float4(0.f, 0.f, 0.f, 0.f);
        for (int k = k0; k < kend; ++k) {
            float4 w4 = *(const float4*)&Wcd[(size_t)k * 64 + 4 * cq];
            float f0 = feat[k];
            s0.x += f0 * w4.x; s0.y += f0 * w4.y; s0.z += f0 * w4.z; s0.w += f0 * w4.w;
        }
        *(float4*)&gp[kh][4 * cq] = s0;
    }
    __syncthreads();
    if (tid < 128) {
        int mt = tid >> 6, c = tid & 63;
        float v = mt ? (hpC[0][c] + hpC[1][c]) : (hpA[0][c] + hpA[1][c]);
        feat[(mt ? 134 : 68) + c] = v;
    }
    __syncthreads();
    {   // gate-part2: k in [68,198), 16 splits of 9
        int cq = tid & 15, kh = tid >> 4;
        int k0 = 68 + 9 * kh;
        int kend = (k0 + 9 < 198) ? (k0 + 9) : 198;
        float4 s0 = make_float4(0.f, 0.f, 0.f, 0.f);
        for (int k = k0; k < kend; ++k) {
            float4 w4 = *(const float4*)&Wcd[(size_t)k * 64 + 4 * cq];
            float f0 = feat[k];
            s0.x += f0 * w4.x; s0.y += f0 * w4.y; s0.z += f0 * w4.z; s0.w += f0 * w4.w;
        }
        *(float4*)&gp[8 + kh][4 * cq] = s0;
    }
    __syncthreads();
    if (tid < 64) {
        int c = tid;
        float a = bcd[c];
        #pragma unroll
        for (int h = 0; h < 24; ++h) a += gp[h][c];
        size_t go = (size_t)b * N_ + i;
        float cnd = tanhf(a);
        float u = ub[go * 64 + c];
        float st = state[go * 64 + c];
        state[go * 64 + c] = u * st + (1.f - u) * cnd;
    }
}

// ======== pred head ========
__global__ void __launch_bounds__(64) k_pred(
        const float* __restrict__ state,
        const float* __restrict__ Wp1, const float* __restrict__ bp1,
        const float* __restrict__ Wp2, const float* __restrict__ bp2,
        float* __restrict__ out) {
    __shared__ float st[64];
    int row = blockIdx.x;
    int tid = threadIdx.x;
    st[tid] = state[row * 64 + tid];
    __syncthreads();
    float acc = bp1[tid];
    #pragma unroll 8
    for (int a = 0; a < 64; ++a) acc += st[a] * Wp1[a * 64 + tid];
    acc = acc > 0.f ? acc : 0.01f * acc;
    float v = acc * Wp2[tid];
    #pragma unroll
    for (int off = 32; off > 0; off >>= 1) v += __shfl_down(v, off);
    if (tid == 0) out[row] = v + bp2[0];
}

extern "C" void kernel_launch(void* const* d_in, const int* in_sizes, int n_in,
                              void* d_out, int out_size, void* d_ws, size_t ws_size,
                              hipStream_t stream) {
    const float* x    = (const float*)d_in[0];
    const float* nf   = (const float*)d_in[1];
    const float* Ws2d = (const float*)d_in[2];
    const float* bs2d = (const float*)d_in[3];
    const float* Wrz  = (const float*)d_in[4];
    const float* brz  = (const float*)d_in[5];
    const float* Wh   = (const float*)d_in[6];
    const float* bh   = (const float*)d_in[7];
    const float* Wc2  = (const float*)d_in[8];
    const float* bc2  = (const float*)d_in[9];
    const float* Wc1  = (const float*)d_in[10];
    const float* bc1  = (const float*)d_in[11];
    const float* Wm2  = (const float*)d_in[12];
    const float* bm2  = (const float*)d_in[13];
    const float* Wm1  = (const float*)d_in[14];
    const float* bm1  = (const float*)d_in[15];
    const float* Wru  = (const float*)d_in[16];
    const float* bru  = (const float*)d_in[17];
    const float* Wcand= (const float*)d_in[18];
    const float* bcand= (const float*)d_in[19];
    const float* Wp1  = (const float*)d_in[20];
    const float* bp1  = (const float*)d_in[21];
    const float* Wp2  = (const float*)d_in[22];
    const float* bp2  = (const float*)d_in[23];
    float* out = (float*)d_out;

    float* ws = (float*)d_ws;
    const size_t PQ = (size_t)T_ * R_ * 32;
    float* Pc = ws;
    float* Qc = Pc + PQ;
    float* Pm = Qc + PQ;
    float* Qm = Pm + PQ;

    const size_t A2F = (size_t)96 * NN_;
    const size_t XHF = (size_t)96 * N_ * 4;
    const size_t FULL_NEED = (A2F + XHF + 3 * (size_t)R_ * 64) * 4;
    bool full = ws_size >= FULL_NEED;

    const float* Aall = out + R_;

    if (full) {
        float* A2base = ws;                  // aliases dead P/Q after k_pairall
        float* xhbase = ws + A2F;
        float* state  = xhbase + XHF;
        float* rs     = state + (size_t)R_ * 64;
        float* ub     = rs + (size_t)R_ * 64;

        k_dyall<<<400, 256, 0, stream>>>(x, nf, Ws2d, bs2d, Wrz, brz, Wh, bh,
                                         Wc2, Wm2, bc2, bm2, Pc, Qc, Pm, Qm, state);
        k_pairall<<<dim3(13, 13, 96), dim3(16, 16), 0, stream>>>(
            Pc, Qc, Pm, Qm, Wc1, bc1, Wm1, bm1, out);
        k_a2<<<96 * 8, 256, 0, stream>>>(Aall, A2base, 96);
        k_xh<<<96, 256, 0, stream>>>(Aall, A2base, x, 0, xhbase);

        for (int t = 0; t < T_; ++t) {
            const float* At  = Aall + (size_t)t * 8 * NN_;
            const float* A2t = A2base + (size_t)t * 8 * NN_;
            const float* xht = xhbase + (size_t)t * 8 * N_ * 4;
            k_ru1  <<<1600, 256, 0, stream>>>(At, A2t, xht, x, t, state, Wru, bru, rs, ub);
            k_cand1<<<1600, 256, 0, stream>>>(At, A2t, xht, x, t, rs, Wcand, bcand, ub, state);
        }
        k_pred<<<R_, 64, 0, stream>>>(state, Wp1, bp1, Wp2, bp2, out);
    } else {
        float* A2base = ws + 4 * PQ;
        float* xhbase = A2base + (size_t)8 * NN_;
        float* state  = xhbase + (size_t)8 * N_ * 4;
        float* rs     = state + (size_t)R_ * 64;
        float* ub     = rs + (size_t)R_ * 64;

        k_dyall<<<400, 256, 0, stream>>>(x, nf, Ws2d, bs2d, Wrz, brz, Wh, bh,
                                         Wc2, Wm2, bc2, bm2, Pc, Qc, Pm, Qm, state);
        k_pairall<<<dim3(13, 13, 96), dim3(16, 16), 0, stream>>>(
            Pc, Qc, Pm, Qm, Wc1, bc1, Wm1, bm1, out);
        for (int t = 0; t < T_; ++t) {
            const float* At = Aall + (size_t)t * 8 * NN_;
            k_a2<<<8 * 8, 256, 0, stream>>>(At, A2base, 8);
            k_xh<<<8, 256, 0, stream>>>(At, A2base, x, t * 8, xhbase);
            k_ru1  <<<1600, 256, 0, stream>>>(At, A2base, xhbase, x, t, state, Wru, bru, rs, ub);
            k_cand1<<<1600, 256, 0, stream>>>(At, A2base, xhbase, x, t, rs, Wcand, bcand, ub, state);
        }
        k_pred<<<R_, 64, 0, stream>>>(state, Wp1, bp1, Wp2, bp2, out);
    }
}

// Round 13
// 457.139 us; speedup vs baseline: 1.0631x; 1.0631x over previous
//
#include <hip/hip_runtime.h>
#include <math.h>

#define B_ 8
#define T_ 12
#define N_ 200
#define R_ 1600    // B*N
#define NN_ 40000  // N*N

__device__ __forceinline__ float sigm(float v) { return 1.f / (1.f + expf(-v)); }

// ======== Phase A: dy-GRU chain + P/Q projections ====
// R9-proven: weights TRANSPOSED in LDS, all inner loops float4 LDS reads.
__global__ void __launch_bounds__(256) k_dyall(
        const float* __restrict__ x,  const float* __restrict__ nf,
        const float* __restrict__ Ws2d, const float* __restrict__ bs2d,
        const float* __restrict__ Wrz,  const float* __restrict__ brz,
        const float* __restrict__ Wh,   const float* __restrict__ bh,
        const float* __restrict__ Wc2,  const float* __restrict__ Wm2,
        const float* __restrict__ bc2,  const float* __restrict__ bm2,
        float* __restrict__ Pc, float* __restrict__ Qc,
        float* __restrict__ Pm, float* __restrict__ Qm,
        float* __restrict__ state) {
    __shared__ alignas(16) float sWs2d[64 * 32];
    __shared__ alignas(16) float sWrzT[64][36];   // [o][i], i 0..32, pad->36
    __shared__ alignas(16) float sWhT[32][36];    // [k][i]
    __shared__ alignas(16) float sWc2T[32][68];   // [k][r], r 0..63, pad->68
    __shared__ alignas(16) float sWm2T[32][68];
    __shared__ float sbrz[64], sbh[32], sbs2d[32], sbc2[32], sbm2[32];
    __shared__ alignas(16) float nfs[4][64], dy[4][32], rz[4][64], s4[4][32];
    __shared__ alignas(16) float in1[4][36], in2[4][36];
    int bk = blockIdx.x, tid = threadIdx.x;
    int w = tid >> 6, o = tid & 63;
    int row = bk * 4 + w, b = row / N_, n = row % N_;
    state[bk * 256 + tid] = 0.f;
    for (int idx = tid; idx < 2048; idx += 256) sWs2d[idx] = Ws2d[idx];
    for (int idx = tid; idx < 2304; idx += 256) {
        int oo = idx / 36, ii = idx % 36;
        sWrzT[oo][ii] = (ii < 33) ? Wrz[ii * 64 + oo] : 0.f;
    }
    for (int idx = tid; idx < 1152; idx += 256) {
        int kk = idx / 36, ii = idx % 36;
        sWhT[kk][ii] = (ii < 33) ? Wh[ii * 32 + kk] : 0.f;
    }
    for (int idx = tid; idx < 2176; idx += 256) {
        int kk = idx / 68, rr = idx % 68;
        float vc = (rr < 64) ? Wc2[rr * 32 + kk] : 0.f;
        float vm = (rr < 64) ? Wm2[rr * 32 + kk] : 0.f;
        sWc2T[kk][rr] = vc; sWm2T[kk][rr] = vm;
    }
    if (tid < 144) { ((float*)in1)[tid] = 0.f; ((float*)in2)[tid] = 0.f; }
    if (tid < 64) sbrz[tid] = brz[tid];
    if (tid < 32) { sbh[tid] = bh[tid]; sbs2d[tid] = bs2d[tid];
                    sbc2[tid] = bc2[tid]; sbm2[tid] = bm2[tid]; }
    nfs[w][o] = nf[n * 64 + o];
    __syncthreads();
    if (o < 32) {
        float acc = sbs2d[o];
        #pragma unroll 8
        for (int i = 0; i < 64; ++i) acc += nfs[w][i] * sWs2d[i * 32 + o];
        dy[w][o] = acc;
    }
    __syncthreads();
    for (int t = 0; t < T_; ++t) {
        if (o == 0) { float v = x[((b * T_ + t) * N_ + n) * 2]; in1[w][0] = v; in2[w][0] = v; }
        if (o < 32) in1[w][o + 1] = dy[w][o];
        __syncthreads();
        float acc = sbrz[o];
        #pragma unroll
        for (int ig = 0; ig < 9; ++ig) {
            float4 w4 = *(const float4*)&sWrzT[o][4 * ig];
            float4 f4 = *(const float4*)&in1[w][4 * ig];
            acc += f4.x * w4.x + f4.y * w4.y + f4.z * w4.z + f4.w * w4.w;
        }
        rz[w][o] = sigm(acc);
        __syncthreads();
        if (o < 32) in2[w][o + 1] = rz[w][o] * dy[w][o];
        __syncthreads();
        if (o < 32) {
            float h = sbh[o];
            #pragma unroll
            for (int ig = 0; ig < 9; ++ig) {
                float4 w4 = *(const float4*)&sWhT[o][4 * ig];
                float4 f4 = *(const float4*)&in2[w][4 * ig];
                h += f4.x * w4.x + f4.y * w4.y + f4.z * w4.z + f4.w * w4.w;
            }
            h = tanhf(h);
            float z = rz[w][32 + o];
            float nd = z * dy[w][o] + (1.f - z) * h;
            dy[w][o] = nd;
            s4[w][o] = nd > 0.f ? nd : 0.f;
        }
        __syncthreads();
        size_t base = ((size_t)t * R_ + row) * 32;
        for (int idx = o; idx < 128; idx += 64) {
            int mat = idx >> 5, k = idx & 31;
            const float* WT = (mat < 2) ? &sWc2T[k][0] : &sWm2T[k][0];
            int rb = (mat & 1) ? 32 : 0;
            float a = (mat == 0) ? sbc2[k] : (mat == 2) ? sbm2[k] : 0.f;
            #pragma unroll
            for (int ig = 0; ig < 8; ++ig) {
                float4 w4 = *(const float4*)&WT[rb + 4 * ig];
                float4 f4 = *(const float4*)&s4[w][4 * ig];
                a += f4.x * w4.x + f4.y * w4.y + f4.z * w4.z + f4.w * w4.w;
            }
            ((mat == 0) ? Pc : (mat == 1) ? Qc : (mat == 2) ? Pm : Qm)[base + k] = a;
        }
        __syncthreads();
    }
}

// ======== Phase B: adjacency — R10-proven 16x16 tile, W in registers ====
__global__ void __launch_bounds__(256) k_pairall(
        const float* __restrict__ Pc, const float* __restrict__ Qc,
        const float* __restrict__ Pm, const float* __restrict__ Qm,
        const float* __restrict__ Wc1, const float* __restrict__ bc1,
        const float* __restrict__ Wm1, const float* __restrict__ bm1,
        float* __restrict__ out) {
    __shared__ float sPc[16][36], sQc[16][36], sPm[16][36], sQm[16][36];
    int z = blockIdx.z;            // t*8 + b
    int i0 = blockIdx.x * 16, j0 = blockIdx.y * 16;
    int tid = threadIdx.y * 16 + threadIdx.x;
    size_t tb = (size_t)z * N_;
    for (int l = tid; l < 128; l += 256) {   // 16 rows x 8 float4
        int r = l >> 3, q = l & 7;
        int gi = i0 + r, gj = j0 + r;
        float4 z4 = make_float4(0.f, 0.f, 0.f, 0.f);
        *(float4*)&sPc[r][4 * q] = (gi < N_) ? *(const float4*)&Pc[(tb + gi) * 32 + 4 * q] : z4;
        *(float4*)&sPm[r][4 * q] = (gi < N_) ? *(const float4*)&Pm[(tb + gi) * 32 + 4 * q] : z4;
        *(float4*)&sQc[r][4 * q] = (gj < N_) ? *(const float4*)&Qc[(tb + gj) * 32 + 4 * q] : z4;
        *(float4*)&sQm[r][4 * q] = (gj < N_) ? *(const float4*)&Qm[(tb + gj) * 32 + 4 * q] : z4;
    }
    float4 wc[8], wm[8];
    #pragma unroll
    for (int kg = 0; kg < 8; ++kg) {
        wc[kg] = *(const float4*)&Wc1[4 * kg];
        wm[kg] = *(const float4*)&Wm1[4 * kg];
    }
    __syncthreads();
    int i = i0 + threadIdx.y, j = j0 + threadIdx.x;
    if (i >= N_ || j >= N_) return;
    int ty = threadIdx.y, tx = threadIdx.x;
    float g0 = 0.f, g1 = 0.f, m0 = 0.f, m1 = 0.f;
    #pragma unroll
    for (int kg = 0; kg < 8; ++kg) {
        float4 pc = *(const float4*)&sPc[ty][4 * kg];
        float4 qc = *(const float4*)&sQc[tx][4 * kg];
        float4 w4 = wc[kg];
        g0 += fmaxf(pc.x + qc.x, 0.f) * w4.x + fmaxf(pc.y + qc.y, 0.f) * w4.y;
        g1 += fmaxf(pc.z + qc.z, 0.f) * w4.z + fmaxf(pc.w + qc.w, 0.f) * w4.w;
        float4 pm = *(const float4*)&sPm[ty][4 * kg];
        float4 qm = *(const float4*)&sQm[tx][4 * kg];
        float4 v4 = wm[kg];
        m0 += fmaxf(pm.x + qm.x, 0.f) * v4.x + fmaxf(pm.y + qm.y, 0.f) * v4.y;
        m1 += fmaxf(pm.z + qm.z, 0.f) * v4.z + fmaxf(pm.w + qm.w, 0.f) * v4.w;
    }
    float g = g0 + g1 + bc1[0];
    float m = m0 + m1 + bm1[0];
    out[R_ + (((size_t)z * N_ + i) * N_ + j)] = g * sigm(m);
}

// ======== A2 = A @ A — 128x64 tile, 256 thr, 8x4 micro, BK=32.
// B read DIRECT from global (L2-hit; panel 50KB, shared by 8 blocks/XCD):
// LDS per k-step drops 3 -> 2 b128 per lane. Bs tile + staging removed.
__global__ void __launch_bounds__(256) k_a2(
        const float* __restrict__ Abase, float* __restrict__ Cbase, int nmat) {
    __shared__ float Ast[32][132];   // [k][i] transposed
    int bx = blockIdx.x;
    int z = bx % nmat, tl = bx / nmat;      // z fastest => XCD-local matrices
    int i0 = (tl >> 2) * 128, j0 = (tl & 3) * 64;
    const float* Az = Abase + (size_t)z * NN_;
    float* Cz = Cbase + (size_t)z * NN_;
    int tid = threadIdx.x;
    int tx = tid & 15, ty = tid >> 4;       // tx: 4-col group, ty: 8-row group
    int jj = j0 + tx * 4;
    bool jok = (jj + 3 < N_);               // N_%4==0 => full float4 valid or fully OOB
    const float* Bp = Az + jj;
    float acc[8][4] = {};
    for (int k0 = 0; k0 < 200; k0 += 32) {
        {   // stage A transposed: 128 i x 32 k
            int i = tid >> 1;                 // 0..127
            int kb = (tid & 1) * 16;          // 0 or 16
            int gi = i0 + i;
            #pragma unroll
            for (int q = 0; q < 4; ++q) {
                int k = kb + q * 4;
                int gk = k0 + k;
                float4 v = make_float4(0.f, 0.f, 0.f, 0.f);
                if (gi < N_) {
                    if (gk + 3 < N_) v = *(const float4*)&Az[gi * N_ + gk];
                    else {
                        float t0 = (gk + 0 < N_) ? Az[gi * N_ + gk + 0] : 0.f;
                        float t1 = (gk + 1 < N_) ? Az[gi * N_ + gk + 1] : 0.f;
                        float t2 = (gk + 2 < N_) ? Az[gi * N_ + gk + 2] : 0.f;
                        float t3 = (gk + 3 < N_) ? Az[gi * N_ + gk + 3] : 0.f;
                        v = make_float4(t0, t1, t2, t3);
                    }
                }
                Ast[k + 0][i] = v.x; Ast[k + 1][i] = v.y;
                Ast[k + 2][i] = v.z; Ast[k + 3][i] = v.w;
            }
        }
        __syncthreads();
        int kmax = (k0 + 32 <= N_) ? 32 : (N_ - k0);   // 32 or 8 — no OOB B rows
        #pragma unroll 8
        for (int k = 0; k < kmax; ++k) {
            float4 a0 = *(const float4*)&Ast[k][ty * 8];
            float4 a1 = *(const float4*)&Ast[k][ty * 8 + 4];
            float4 bv = jok ? *(const float4*)&Bp[(size_t)(k0 + k) * N_]
                            : make_float4(0.f, 0.f, 0.f, 0.f);
            acc[0][0] += a0.x * bv.x; acc[0][1] += a0.x * bv.y; acc[0][2] += a0.x * bv.z; acc[0][3] += a0.x * bv.w;
            acc[1][0] += a0.y * bv.x; acc[1][1] += a0.y * bv.y; acc[1][2] += a0.y * bv.z; acc[1][3] += a0.y * bv.w;
            acc[2][0] += a0.z * bv.x; acc[2][1] += a0.z * bv.y; acc[2][2] += a0.z * bv.z; acc[2][3] += a0.z * bv.w;
            acc[3][0] += a0.w * bv.x; acc[3][1] += a0.w * bv.y; acc[3][2] += a0.w * bv.z; acc[3][3] += a0.w * bv.w;
            acc[4][0] += a1.x * bv.x; acc[4][1] += a1.x * bv.y; acc[4][2] += a1.x * bv.z; acc[4][3] += a1.x * bv.w;
            acc[5][0] += a1.y * bv.x; acc[5][1] += a1.y * bv.y; acc[5][2] += a1.y * bv.z; acc[5][3] += a1.y * bv.w;
            acc[6][0] += a1.z * bv.x; acc[6][1] += a1.z * bv.y; acc[6][2] += a1.z * bv.z; acc[6][3] += a1.z * bv.w;
            acc[7][0] += a1.w * bv.x; acc[7][1] += a1.w * bv.y; acc[7][2] += a1.w * bv.z; acc[7][3] += a1.w * bv.w;
        }
        __syncthreads();
    }
    #pragma unroll
    for (int r = 0; r < 8; ++r) {
        int gi = i0 + ty * 8 + r;
        if (gi >= N_) continue;
        if (jok) {
            *(float4*)&Cz[gi * N_ + jj] = make_float4(acc[r][0], acc[r][1], acc[r][2], acc[r][3]);
        }
    }
}

// ======== xt-hops: xh[zl][i][4] = {A@x0, A@x1, A2@x0, A2@x1} ========
__global__ void __launch_bounds__(256) k_xh(
        const float* __restrict__ Abase, const float* __restrict__ A2base,
        const float* __restrict__ x, int z0, float* __restrict__ xh) {
    __shared__ float xtl[400];
    int zl = blockIdx.x, tid = threadIdx.x;
    int z = z0 + zl, t = z >> 3, b = z & 7;
    int w = tid >> 6, l = tid & 63;
    const float* xb = x + ((size_t)(b * T_ + t)) * N_ * 2;
    for (int idx = tid; idx < 400; idx += 256) xtl[idx] = xb[idx];
    __syncthreads();
    for (int it = 0; it < 50; ++it) {
        int i = it * 4 + w;
        float p0 = 0.f, p1 = 0.f, p2 = 0.f, p3 = 0.f;
        if (l < 50) {
            float4 a4 = *(const float4*)(Abase + (size_t)zl * NN_ + i * 200 + 4 * l);
            float4 c4 = *(const float4*)(A2base + (size_t)zl * NN_ + i * 200 + 4 * l);
            #pragma unroll
            for (int q = 0; q < 4; ++q) {
                float av = (&a4.x)[q], cv = (&c4.x)[q];
                float x0 = xtl[(4 * l + q) * 2], x1 = xtl[(4 * l + q) * 2 + 1];
                p0 += av * x0; p1 += av * x1; p2 += cv * x0; p3 += cv * x1;
            }
        }
        #pragma unroll
        for (int off = 32; off > 0; off >>= 1) {
            p0 += __shfl_down(p0, off); p1 += __shfl_down(p1, off);
            p2 += __shfl_down(p2, off); p3 += __shfl_down(p3, off);
        }
        if (l == 0) *(float4*)(xh + ((size_t)zl * N_ + i) * 4) = make_float4(p0, p1, p2, p3);
    }
}

// ======== K1: R11-proven wave-specialized (2 rows/block, 800 blocks) ========
__global__ void __launch_bounds__(256) k_ru2(
        const float* __restrict__ At, const float* __restrict__ A2t,
        const float* __restrict__ xht,
        const float* __restrict__ x, int t, const float* __restrict__ state,
        const float* __restrict__ Wru, const float* __restrict__ bru,
        float* __restrict__ rs, float* __restrict__ ub) {
    __shared__ float a2s[2 * 200], c2s[2 * 200];
    __shared__ float hpA[2][2][64], hpC[2][2][64];   // [h][r][c]
    __shared__ float feat[2][200];
    __shared__ float gp[12][2][128];                 // part1: 0..3, part2: 4..11
    int bx = blockIdx.x;
    int b = bx & 7, i0 = (bx >> 3) * 2;      // b == XCD -> state stays L2-local
    int tid = threadIdx.x;
    const float* F = state + (size_t)b * (N_ * 64);
    {   // stage: A/A2 rows, F->feat[.][2..65], x->[0..1], xh->[66..67],[132..133]
        const float4* Ar = (const float4*)(At + ((size_t)b * N_ + i0) * 200);
        const float4* Cr = (const float4*)(A2t + ((size_t)b * N_ + i0) * 200);
        if (tid < 100) { ((float4*)a2s)[tid] = Ar[tid]; ((float4*)c2s)[tid] = Cr[tid]; }
        if (tid >= 100 && tid < 164) {
            int l = tid - 100, r = l >> 5, q = l & 31;
            *(float2*)&feat[r][2 + 2 * q] = *(const float2*)&F[(size_t)(i0 + r) * 64 + 2 * q];
        }
        if (tid >= 164 && tid < 168) {
            int l = tid - 164;
            feat[l >> 1][l & 1] = x[((size_t)(b * T_ + t) * N_ + i0 + (l >> 1)) * 2 + (l & 1)];
        }
        if (tid >= 168 && tid < 176) {
            int l = tid - 168, rr = l >> 2, q = l & 3;
            feat[rr][(q < 2) ? (66 + q) : (132 + q - 2)] = xht[((size_t)b * N_ + i0 + rr) * 4 + q];
        }
    }
    __syncthreads();
    int w = tid >> 6, lane = tid & 63;
    if (w < 2) {   // hop: wave h = w owns j-half, computes BOTH rows
        int h = w;
        int cg = lane & 15, jq = lane >> 4;
        const float* a0p = a2s + h * 100;
        const float* a1p = a2s + 200 + h * 100;
        const float* c0p = c2s + h * 100;
        const float* c1p = c2s + 200 + h * 100;
        const float* Fb = F + (size_t)(h * 100) * 64 + 4 * cg;
        float4 aA0 = make_float4(0.f, 0.f, 0.f, 0.f), aA1 = aA0, aC0 = aA0, aC1 = aA0;
        #pragma unroll 5
        for (int m = 0; m < 25; ++m) {
            int j = jq + 4 * m;
            float4 f4 = *(const float4*)&Fb[(size_t)j * 64];
            float a0 = a0p[j], a1 = a1p[j], c0 = c0p[j], c1 = c1p[j];
            aA0.x += a0 * f4.x; aA0.y += a0 * f4.y; aA0.z += a0 * f4.z; aA0.w += a0 * f4.w;
            aA1.x += a1 * f4.x; aA1.y += a1 * f4.y; aA1.z += a1 * f4.z; aA1.w += a1 * f4.w;
            aC0.x += c0 * f4.x; aC0.y += c0 * f4.y; aC0.z += c0 * f4.z; aC0.w += c0 * f4.w;
            aC1.x += c1 * f4.x; aC1.y += c1 * f4.y; aC1.z += c1 * f4.z; aC1.w += c1 * f4.w;
        }
        #pragma unroll
        for (int off = 16; off <= 32; off <<= 1) {
            aA0.x += __shfl_xor(aA0.x, off); aA0.y += __shfl_xor(aA0.y, off);
            aA0.z += __shfl_xor(aA0.z, off); aA0.w += __shfl_xor(aA0.w, off);
            aA1.x += __shfl_xor(aA1.x, off); aA1.y += __shfl_xor(aA1.y, off);
            aA1.z += __shfl_xor(aA1.z, off); aA1.w += __shfl_xor(aA1.w, off);
            aC0.x += __shfl_xor(aC0.x, off); aC0.y += __shfl_xor(aC0.y, off);
            aC0.z += __shfl_xor(aC0.z, off); aC0.w += __shfl_xor(aC0.w, off);
            aC1.x += __shfl_xor(aC1.x, off); aC1.y += __shfl_xor(aC1.y, off);
            aC1.z += __shfl_xor(aC1.z, off); aC1.w += __shfl_xor(aC1.w, off);
        }
        if (lane < 16) {
            *(float4*)&hpA[h][0][4 * cg] = aA0;
            *(float4*)&hpA[h][1][4 * cg] = aA1;
            *(float4*)&hpC[h][0][4 * cg] = aC0;
            *(float4*)&hpC[h][1][4 * cg] = aC1;
        }
    } else {   // gate-part1: k in [0,68), features ready after stage
        int l = tid - 128;            // 0..127
        int cq = l & 31, kh = l >> 5; // kh 0..3
        int k0 = 17 * kh, kend = (k0 + 17 < 68) ? (k0 + 17) : 68;
        float4 s0 = make_float4(0.f, 0.f, 0.f, 0.f);
        float4 s1 = make_float4(0.f, 0.f, 0.f, 0.f);
        for (int k = k0; k < kend; ++k) {
            float4 w4 = *(const float4*)&Wru[(size_t)k * 128 + 4 * cq];
            float f0 = feat[0][k], f1 = feat[1][k];
            s0.x += f0 * w4.x; s0.y += f0 * w4.y; s0.z += f0 * w4.z; s0.w += f0 * w4.w;
            s1.x += f1 * w4.x; s1.y += f1 * w4.y; s1.z += f1 * w4.z; s1.w += f1 * w4.w;
        }
        *(float4*)&gp[kh][0][4 * cq] = s0;
        *(float4*)&gp[kh][1][4 * cq] = s1;
    }
    __syncthreads();
    {   // combine j-halves into feat[68..131], [134..197]
        int mt = tid >> 7, r = (tid >> 6) & 1, c = tid & 63;
        float v = mt ? (hpC[0][r][c] + hpC[1][r][c]) : (hpA[0][r][c] + hpA[1][r][c]);
        feat[r][(mt ? 134 : 68) + c] = v;
    }
    __syncthreads();
    {   // gate-part2: k in [68,198), 8 splits of 17 (last 11)
        int cq = tid & 31, kh = tid >> 5;
        int k0 = 68 + 17 * kh, kend = (k0 + 17 < 198) ? (k0 + 17) : 198;
        float4 s0 = make_float4(0.f, 0.f, 0.f, 0.f);
        float4 s1 = make_float4(0.f, 0.f, 0.f, 0.f);
        for (int k = k0; k < kend; ++k) {
            float4 w4 = *(const float4*)&Wru[(size_t)k * 128 + 4 * cq];
            float f0 = feat[0][k], f1 = feat[1][k];
            s0.x += f0 * w4.x; s0.y += f0 * w4.y; s0.z += f0 * w4.z; s0.w += f0 * w4.w;
            s1.x += f1 * w4.x; s1.y += f1 * w4.y; s1.z += f1 * w4.z; s1.w += f1 * w4.w;
        }
        *(float4*)&gp[4 + kh][0][4 * cq] = s0;
        *(float4*)&gp[4 + kh][1][4 * cq] = s1;
    }
    __syncthreads();
    {   // reduce + activation + store
        int rq = tid >> 7, c = tid & 127;
        float a = bru[c];
        #pragma unroll
        for (int h = 0; h < 12; ++h) a += gp[h][rq][c];
        float v = sigm(a);
        size_t go = (size_t)b * N_ + i0 + rq;
        if (c < 64) rs[go * 64 + c] = v * feat[rq][2 + c];
        else        ub[go * 64 + (c - 64)] = v;
    }
}

// ======== K2: R11-proven wave-specialized, 64-col gate ========
__global__ void __launch_bounds__(256) k_cand2(
        const float* __restrict__ At, const float* __restrict__ A2t,
        const float* __restrict__ xht,
        const float* __restrict__ x, int t, const float* __restrict__ rsin,
        const float* __restrict__ Wcd, const float* __restrict__ bcd,
        const float* __restrict__ ub, float* __restrict__ state) {
    __shared__ float a2s[2 * 200], c2s[2 * 200];
    __shared__ float hpA[2][2][64], hpC[2][2][64];
    __shared__ float feat[2][200];
    __shared__ float gp[24][2][64];                  // part1: 0..7, part2: 8..23
    int bx = blockIdx.x;
    int b = bx & 7, i0 = (bx >> 3) * 2;
    int tid = threadIdx.x;
    const float* F = rsin + (size_t)b * (N_ * 64);
    {
        const float4* Ar = (const float4*)(At + ((size_t)b * N_ + i0) * 200);
        const float4* Cr = (const float4*)(A2t + ((size_t)b * N_ + i0) * 200);
        if (tid < 100) { ((float4*)a2s)[tid] = Ar[tid]; ((float4*)c2s)[tid] = Cr[tid]; }
        if (tid >= 100 && tid < 164) {
            int l = tid - 100, r = l >> 5, q = l & 31;
            *(float2*)&feat[r][2 + 2 * q] = *(const float2*)&F[(size_t)(i0 + r) * 64 + 2 * q];
        }
        if (tid >= 164 && tid < 168) {
            int l = tid - 164;
            feat[l >> 1][l & 1] = x[((size_t)(b * T_ + t) * N_ + i0 + (l >> 1)) * 2 + (l & 1)];
        }
        if (tid >= 168 && tid < 176) {
            int l = tid - 168, rr = l >> 2, q = l & 3;
            feat[rr][(q < 2) ? (66 + q) : (132 + q - 2)] = xht[((size_t)b * N_ + i0 + rr) * 4 + q];
        }
    }
    __syncthreads();
    int w = tid >> 6, lane = tid & 63;
    if (w < 2) {   // hop over rs, 1 F load -> both rows
        int h = w;
        int cg = lane & 15, jq = lane >> 4;
        const float* a0p = a2s + h * 100;
        const float* a1p = a2s + 200 + h * 100;
        const float* c0p = c2s + h * 100;
        const float* c1p = c2s + 200 + h * 100;
        const float* Fb = F + (size_t)(h * 100) * 64 + 4 * cg;
        float4 aA0 = make_float4(0.f, 0.f, 0.f, 0.f), aA1 = aA0, aC0 = aA0, aC1 = aA0;
        #pragma unroll 5
        for (int m = 0; m < 25; ++m) {
            int j = jq + 4 * m;
            float4 f4 = *(const float4*)&Fb[(size_t)j * 64];
            float a0 = a0p[j], a1 = a1p[j], c0 = c0p[j], c1 = c1p[j];
            aA0.x += a0 * f4.x; aA0.y += a0 * f4.y; aA0.z += a0 * f4.z; aA0.w += a0 * f4.w;
            aA1.x += a1 * f4.x; aA1.y += a1 * f4.y; aA1.z += a1 * f4.z; aA1.w += a1 * f4.w;
            aC0.x += c0 * f4.x; aC0.y += c0 * f4.y; aC0.z += c0 * f4.z; aC0.w += c0 * f4.w;
            aC1.x += c1 * f4.x; aC1.y += c1 * f4.y; aC1.z += c1 * f4.z; aC1.w += c1 * f4.w;
        }
        #pragma unroll
        for (int off = 16; off <= 32; off <<= 1) {
            aA0.x += __shfl_xor(aA0.x, off); aA0.y += __shfl_xor(aA0.y, off);
            aA0.z += __shfl_xor(aA0.z, off); aA0.w += __shfl_xor(aA0.w, off);
            aA1.x += __shfl_xor(aA1.x, off); aA1.y += __shfl_xor(aA1.y, off);
            aA1.z += __shfl_xor(aA1.z, off); aA1.w += __shfl_xor(aA1.w, off);
            aC0.x += __shfl_xor(aC0.x, off); aC0.y += __shfl_xor(aC0.y, off);
            aC0.z += __shfl_xor(aC0.z, off); aC0.w += __shfl_xor(aC0.w, off);
            aC1.x += __shfl_xor(aC1.x, off); aC1.y += __shfl_xor(aC1.y, off);
            aC1.z += __shfl_xor(aC1.z, off); aC1.w += __shfl_xor(aC1.w, off);
        }
        if (lane < 16) {
            *(float4*)&hpA[h][0][4 * cg] = aA0;
            *(float4*)&hpA[h][1][4 * cg] = aA1;
            *(float4*)&hpC[h][0][4 * cg] = aC0;
            *(float4*)&hpC[h][1][4 * cg] = aC1;
        }
    } else {   // gate-part1: k in [0,68)
        int l = tid - 128;            // 0..127
        int cq = l & 15, kh = l >> 4; // kh 0..7
        int k0 = 9 * kh, kend = (k0 + 9 < 68) ? (k0 + 9) : 68;
        float4 s0 = make_float4(0.f, 0.f, 0.f, 0.f);
        float4 s1 = make_float4(0.f, 0.f, 0.f, 0.f);
        for (int k = k0; k < kend; ++k) {
            float4 w4 = *(const float4*)&Wcd[(size_t)k * 64 + 4 * cq];
            float f0 = feat[0][k], f1 = feat[1][k];
            s0.x += f0 * w4.x; s0.y += f0 * w4.y; s0.z += f0 * w4.z; s0.w += f0 * w4.w;
            s1.x += f1 * w4.x; s1.y += f1 * w4.y; s1.z += f1 * w4.z; s1.w += f1 * w4.w;
        }
        *(float4*)&gp[kh][0][4 * cq] = s0;
        *(float4*)&gp[kh][1][4 * cq] = s1;
    }
    __syncthreads();
    {
        int mt = tid >> 7, r = (tid >> 6) & 1, c = tid & 63;
        float v = mt ? (hpC[0][r][c] + hpC[1][r][c]) : (hpA[0][r][c] + hpA[1][r][c]);
        feat[r][(mt ? 134 : 68) + c] = v;
    }
    __syncthreads();
    {   // gate-part2: k in [68,198), 16 splits of 9
        int cq = tid & 15, kh = tid >> 4;
        int k0 = 68 + 9 * kh;
        int kend = (k0 + 9 < 198) ? (k0 + 9) : 198;
        float4 s0 = make_float4(0.f, 0.f, 0.f, 0.f);
        float4 s1 = make_float4(0.f, 0.f, 0.f, 0.f);
        for (int k = k0; k < kend; ++k) {
            float4 w4 = *(const float4*)&Wcd[(size_t)k * 64 + 4 * cq];
            float f0 = feat[0][k], f1 = feat[1][k];
            s0.x += f0 * w4.x; s0.y += f0 * w4.y; s0.z += f0 * w4.z; s0.w += f0 * w4.w;
            s1.x += f1 * w4.x; s1.y += f1 * w4.y; s1.z += f1 * w4.z; s1.w += f1 * w4.w;
        }
        *(float4*)&gp[8 + kh][0][4 * cq] = s0;
        *(float4*)&gp[8 + kh][1][4 * cq] = s1;
    }
    __syncthreads();
    if (tid < 128) {
        int rq = tid >> 6, c = tid & 63;
        float a = bcd[c];
        #pragma unroll
        for (int h = 0; h < 24; ++h) a += gp[h][rq][c];
        size_t go = (size_t)b * N_ + i0 + rq;
        float cnd = tanhf(a);
        float u = ub[go * 64 + c];
        float st = state[go * 64 + c];
        state[go * 64 + c] = u * st + (1.f - u) * cnd;
    }
}

// ======== pred head ========
__global__ void __launch_bounds__(64) k_pred(
        const float* __restrict__ state,
        const float* __restrict__ Wp1, const float* __restrict__ bp1,
        const float* __restrict__ Wp2, const float* __restrict__ bp2,
        float* __restrict__ out) {
    __shared__ float st[64];
    int row = blockIdx.x;
    int tid = threadIdx.x;
    st[tid] = state[row * 64 + tid];
    __syncthreads();
    float acc = bp1[tid];
    #pragma unroll 8
    for (int a = 0; a < 64; ++a) acc += st[a] * Wp1[a * 64 + tid];
    acc = acc > 0.f ? acc : 0.01f * acc;
    float v = acc * Wp2[tid];
    #pragma unroll
    for (int off = 32; off > 0; off >>= 1) v += __shfl_down(v, off);
    if (tid == 0) out[row] = v + bp2[0];
}

extern "C" void kernel_launch(void* const* d_in, const int* in_sizes, int n_in,
                              void* d_out, int out_size, void* d_ws, size_t ws_size,
                              hipStream_t stream) {
    const float* x    = (const float*)d_in[0];
    const float* nf   = (const float*)d_in[1];
    const float* Ws2d = (const float*)d_in[2];
    const float* bs2d = (const float*)d_in[3];
    const float* Wrz  = (const float*)d_in[4];
    const float* brz  = (const float*)d_in[5];
    const float* Wh   = (const float*)d_in[6];
    const float* bh   = (const float*)d_in[7];
    const float* Wc2  = (const float*)d_in[8];
    const float* bc2  = (const float*)d_in[9];
    const float* Wc1  = (const float*)d_in[10];
    const float* bc1  = (const float*)d_in[11];
    const float* Wm2  = (const float*)d_in[12];
    const float* bm2  = (const float*)d_in[13];
    const float* Wm1  = (const float*)d_in[14];
    const float* bm1  = (const float*)d_in[15];
    const float* Wru  = (const float*)d_in[16];
    const float* bru  = (const float*)d_in[17];
    const float* Wcand= (const float*)d_in[18];
    const float* bcand= (const float*)d_in[19];
    const float* Wp1  = (const float*)d_in[20];
    const float* bp1  = (const float*)d_in[21];
    const float* Wp2  = (const float*)d_in[22];
    const float* bp2  = (const float*)d_in[23];
    float* out = (float*)d_out;

    float* ws = (float*)d_ws;
    const size_t PQ = (size_t)T_ * R_ * 32;
    float* Pc = ws;
    float* Qc = Pc + PQ;
    float* Pm = Qc + PQ;
    float* Qm = Pm + PQ;

    const size_t A2F = (size_t)96 * NN_;
    const size_t XHF = (size_t)96 * N_ * 4;
    const size_t FULL_NEED = (A2F + XHF + 3 * (size_t)R_ * 64) * 4;
    bool full = ws_size >= FULL_NEED;

    const float* Aall = out + R_;

    if (full) {
        float* A2base = ws;                  // aliases dead P/Q after k_pairall
        float* xhbase = ws + A2F;
        float* state  = xhbase + XHF;
        float* rs     = state + (size_t)R_ * 64;
        float* ub     = rs + (size_t)R_ * 64;

        k_dyall<<<400, 256, 0, stream>>>(x, nf, Ws2d, bs2d, Wrz, brz, Wh, bh,
                                         Wc2, Wm2, bc2, bm2, Pc, Qc, Pm, Qm, state);
        k_pairall<<<dim3(13, 13, 96), dim3(16, 16), 0, stream>>>(
            Pc, Qc, Pm, Qm, Wc1, bc1, Wm1, bm1, out);
        k_a2<<<96 * 8, 256, 0, stream>>>(Aall, A2base, 96);
        k_xh<<<96, 256, 0, stream>>>(Aall, A2base, x, 0, xhbase);

        for (int t = 0; t < T_; ++t) {
            const float* At  = Aall + (size_t)t * 8 * NN_;
            const float* A2t = A2base + (size_t)t * 8 * NN_;
            const float* xht = xhbase + (size_t)t * 8 * N_ * 4;
            k_ru2  <<<800, 256, 0, stream>>>(At, A2t, xht, x, t, state, Wru, bru, rs, ub);
            k_cand2<<<800, 256, 0, stream>>>(At, A2t, xht, x, t, rs, Wcand, bcand, ub, state);
        }
        k_pred<<<R_, 64, 0, stream>>>(state, Wp1, bp1, Wp2, bp2, out);
    } else {
        float* A2base = ws + 4 * PQ;
        float* xhbase = A2base + (size_t)8 * NN_;
        float* state  = xhbase + (size_t)8 * N_ * 4;
        float* rs     = state + (size_t)R_ * 64;
        float* ub     = rs + (size_t)R_ * 64;

        k_dyall<<<400, 256, 0, stream>>>(x, nf, Ws2d, bs2d, Wrz, brz, Wh, bh,
                                         Wc2, Wm2, bc2, bm2, Pc, Qc, Pm, Qm, state);
        k_pairall<<<dim3(13, 13, 96), dim3(16, 16), 0, stream>>>(
            Pc, Qc, Pm, Qm, Wc1, bc1, Wm1, bm1, out);
        for (int t = 0; t < T_; ++t) {
            const float* At = Aall + (size_t)t * 8 * NN_;
            k_a2<<<8 * 8, 256, 0, stream>>>(At, A2base, 8);
            k_xh<<<8, 256, 0, stream>>>(At, A2base, x, t * 8, xhbase);
            k_ru2  <<<800, 256, 0, stream>>>(At, A2base, xhbase, x, t, state, Wru, bru, rs, ub);
            k_cand2<<<800, 256, 0, stream>>>(At, A2base, xhbase, x, t, rs, Wcand, bcand, ub, state);
        }
        k_pred<<<R_, 64, 0, stream>>>(state, Wp1, bp1, Wp2, bp2, out);
    }
}

// Round 14
// 452.371 us; speedup vs baseline: 1.0744x; 1.0105x over previous
//
#include <hip/hip_runtime.h>
#include <math.h>

#define B_ 8
#define T_ 12
#define N_ 200
#define R_ 1600    // B*N
#define NN_ 40000  // N*N

__device__ __forceinline__ float sigm(float v) { return 1.f / (1.f + expf(-v)); }

// ======== Phase A: dy-GRU chain + P/Q projections ====
// R9-proven: weights TRANSPOSED in LDS, all inner loops float4 LDS reads.
__global__ void __launch_bounds__(256) k_dyall(
        const float* __restrict__ x,  const float* __restrict__ nf,
        const float* __restrict__ Ws2d, const float* __restrict__ bs2d,
        const float* __restrict__ Wrz,  const float* __restrict__ brz,
        const float* __restrict__ Wh,   const float* __restrict__ bh,
        const float* __restrict__ Wc2,  const float* __restrict__ Wm2,
        const float* __restrict__ bc2,  const float* __restrict__ bm2,
        float* __restrict__ Pc, float* __restrict__ Qc,
        float* __restrict__ Pm, float* __restrict__ Qm,
        float* __restrict__ state) {
    __shared__ alignas(16) float sWs2d[64 * 32];
    __shared__ alignas(16) float sWrzT[64][36];   // [o][i], i 0..32, pad->36
    __shared__ alignas(16) float sWhT[32][36];    // [k][i]
    __shared__ alignas(16) float sWc2T[32][68];   // [k][r], r 0..63, pad->68
    __shared__ alignas(16) float sWm2T[32][68];
    __shared__ float sbrz[64], sbh[32], sbs2d[32], sbc2[32], sbm2[32];
    __shared__ alignas(16) float nfs[4][64], dy[4][32], rz[4][64], s4[4][32];
    __shared__ alignas(16) float in1[4][36], in2[4][36];
    int bk = blockIdx.x, tid = threadIdx.x;
    int w = tid >> 6, o = tid & 63;
    int row = bk * 4 + w, b = row / N_, n = row % N_;
    state[bk * 256 + tid] = 0.f;
    for (int idx = tid; idx < 2048; idx += 256) sWs2d[idx] = Ws2d[idx];
    for (int idx = tid; idx < 2304; idx += 256) {
        int oo = idx / 36, ii = idx % 36;
        sWrzT[oo][ii] = (ii < 33) ? Wrz[ii * 64 + oo] : 0.f;
    }
    for (int idx = tid; idx < 1152; idx += 256) {
        int kk = idx / 36, ii = idx % 36;
        sWhT[kk][ii] = (ii < 33) ? Wh[ii * 32 + kk] : 0.f;
    }
    for (int idx = tid; idx < 2176; idx += 256) {
        int kk = idx / 68, rr = idx % 68;
        float vc = (rr < 64) ? Wc2[rr * 32 + kk] : 0.f;
        float vm = (rr < 64) ? Wm2[rr * 32 + kk] : 0.f;
        sWc2T[kk][rr] = vc; sWm2T[kk][rr] = vm;
    }
    if (tid < 144) { ((float*)in1)[tid] = 0.f; ((float*)in2)[tid] = 0.f; }
    if (tid < 64) sbrz[tid] = brz[tid];
    if (tid < 32) { sbh[tid] = bh[tid]; sbs2d[tid] = bs2d[tid];
                    sbc2[tid] = bc2[tid]; sbm2[tid] = bm2[tid]; }
    nfs[w][o] = nf[n * 64 + o];
    __syncthreads();
    if (o < 32) {
        float acc = sbs2d[o];
        #pragma unroll 8
        for (int i = 0; i < 64; ++i) acc += nfs[w][i] * sWs2d[i * 32 + o];
        dy[w][o] = acc;
    }
    __syncthreads();
    for (int t = 0; t < T_; ++t) {
        if (o == 0) { float v = x[((b * T_ + t) * N_ + n) * 2]; in1[w][0] = v; in2[w][0] = v; }
        if (o < 32) in1[w][o + 1] = dy[w][o];
        __syncthreads();
        float acc = sbrz[o];
        #pragma unroll
        for (int ig = 0; ig < 9; ++ig) {
            float4 w4 = *(const float4*)&sWrzT[o][4 * ig];
            float4 f4 = *(const float4*)&in1[w][4 * ig];
            acc += f4.x * w4.x + f4.y * w4.y + f4.z * w4.z + f4.w * w4.w;
        }
        rz[w][o] = sigm(acc);
        __syncthreads();
        if (o < 32) in2[w][o + 1] = rz[w][o] * dy[w][o];
        __syncthreads();
        if (o < 32) {
            float h = sbh[o];
            #pragma unroll
            for (int ig = 0; ig < 9; ++ig) {
                float4 w4 = *(const float4*)&sWhT[o][4 * ig];
                float4 f4 = *(const float4*)&in2[w][4 * ig];
                h += f4.x * w4.x + f4.y * w4.y + f4.z * w4.z + f4.w * w4.w;
            }
            h = tanhf(h);
            float z = rz[w][32 + o];
            float nd = z * dy[w][o] + (1.f - z) * h;
            dy[w][o] = nd;
            s4[w][o] = nd > 0.f ? nd : 0.f;
        }
        __syncthreads();
        size_t base = ((size_t)t * R_ + row) * 32;
        for (int idx = o; idx < 128; idx += 64) {
            int mat = idx >> 5, k = idx & 31;
            const float* WT = (mat < 2) ? &sWc2T[k][0] : &sWm2T[k][0];
            int rb = (mat & 1) ? 32 : 0;
            float a = (mat == 0) ? sbc2[k] : (mat == 2) ? sbm2[k] : 0.f;
            #pragma unroll
            for (int ig = 0; ig < 8; ++ig) {
                float4 w4 = *(const float4*)&WT[rb + 4 * ig];
                float4 f4 = *(const float4*)&s4[w][4 * ig];
                a += f4.x * w4.x + f4.y * w4.y + f4.z * w4.z + f4.w * w4.w;
            }
            ((mat == 0) ? Pc : (mat == 1) ? Qc : (mat == 2) ? Pm : Qm)[base + k] = a;
        }
        __syncthreads();
    }
}

// ======== Phase B: adjacency — R10-proven 16x16 tile, W in registers ====
__global__ void __launch_bounds__(256) k_pairall(
        const float* __restrict__ Pc, const float* __restrict__ Qc,
        const float* __restrict__ Pm, const float* __restrict__ Qm,
        const float* __restrict__ Wc1, const float* __restrict__ bc1,
        const float* __restrict__ Wm1, const float* __restrict__ bm1,
        float* __restrict__ out) {
    __shared__ float sPc[16][36], sQc[16][36], sPm[16][36], sQm[16][36];
    int z = blockIdx.z;            // t*8 + b
    int i0 = blockIdx.x * 16, j0 = blockIdx.y * 16;
    int tid = threadIdx.y * 16 + threadIdx.x;
    size_t tb = (size_t)z * N_;
    for (int l = tid; l < 128; l += 256) {   // 16 rows x 8 float4
        int r = l >> 3, q = l & 7;
        int gi = i0 + r, gj = j0 + r;
        float4 z4 = make_float4(0.f, 0.f, 0.f, 0.f);
        *(float4*)&sPc[r][4 * q] = (gi < N_) ? *(const float4*)&Pc[(tb + gi) * 32 + 4 * q] : z4;
        *(float4*)&sPm[r][4 * q] = (gi < N_) ? *(const float4*)&Pm[(tb + gi) * 32 + 4 * q] : z4;
        *(float4*)&sQc[r][4 * q] = (gj < N_) ? *(const float4*)&Qc[(tb + gj) * 32 + 4 * q] : z4;
        *(float4*)&sQm[r][4 * q] = (gj < N_) ? *(const float4*)&Qm[(tb + gj) * 32 + 4 * q] : z4;
    }
    float4 wc[8], wm[8];
    #pragma unroll
    for (int kg = 0; kg < 8; ++kg) {
        wc[kg] = *(const float4*)&Wc1[4 * kg];
        wm[kg] = *(const float4*)&Wm1[4 * kg];
    }
    __syncthreads();
    int i = i0 + threadIdx.y, j = j0 + threadIdx.x;
    if (i >= N_ || j >= N_) return;
    int ty = threadIdx.y, tx = threadIdx.x;
    float g0 = 0.f, g1 = 0.f, m0 = 0.f, m1 = 0.f;
    #pragma unroll
    for (int kg = 0; kg < 8; ++kg) {
        float4 pc = *(const float4*)&sPc[ty][4 * kg];
        float4 qc = *(const float4*)&sQc[tx][4 * kg];
        float4 w4 = wc[kg];
        g0 += fmaxf(pc.x + qc.x, 0.f) * w4.x + fmaxf(pc.y + qc.y, 0.f) * w4.y;
        g1 += fmaxf(pc.z + qc.z, 0.f) * w4.z + fmaxf(pc.w + qc.w, 0.f) * w4.w;
        float4 pm = *(const float4*)&sPm[ty][4 * kg];
        float4 qm = *(const float4*)&sQm[tx][4 * kg];
        float4 v4 = wm[kg];
        m0 += fmaxf(pm.x + qm.x, 0.f) * v4.x + fmaxf(pm.y + qm.y, 0.f) * v4.y;
        m1 += fmaxf(pm.z + qm.z, 0.f) * v4.z + fmaxf(pm.w + qm.w, 0.f) * v4.w;
    }
    float g = g0 + g1 + bc1[0];
    float m = m0 + m1 + bm1[0];
    out[R_ + (((size_t)z * N_ + i) * N_ + j)] = g * sigm(m);
}

// ======== A2 = A @ A — R1-proven: 128x64 tile, 256 thr, 8x4 micro, BK=32 ==
__global__ void __launch_bounds__(256) k_a2(
        const float* __restrict__ Abase, float* __restrict__ Cbase, int nmat) {
    __shared__ float Ast[32][132];   // [k][i] transposed
    __shared__ float Bs[32][68];     // [k][j]
    int bx = blockIdx.x;
    int z = bx % nmat, tl = bx / nmat;      // z fastest => XCD-local matrices
    int i0 = (tl >> 2) * 128, j0 = (tl & 3) * 64;
    const float* Az = Abase + (size_t)z * NN_;
    float* Cz = Cbase + (size_t)z * NN_;
    int tid = threadIdx.x;
    int tx = tid & 15, ty = tid >> 4;       // tx: 4-col group, ty: 8-row group
    float acc[8][4] = {};
    for (int k0 = 0; k0 < 200; k0 += 32) {
        {
            int i = tid >> 1;                 // 0..127
            int kb = (tid & 1) * 16;          // 0 or 16
            int gi = i0 + i;
            #pragma unroll
            for (int q = 0; q < 4; ++q) {
                int k = kb + q * 4;
                int gk = k0 + k;
                float4 v = make_float4(0.f, 0.f, 0.f, 0.f);
                if (gi < N_) {
                    if (gk + 3 < N_) v = *(const float4*)&Az[gi * N_ + gk];
                    else {
                        float t0 = (gk + 0 < N_) ? Az[gi * N_ + gk + 0] : 0.f;
                        float t1 = (gk + 1 < N_) ? Az[gi * N_ + gk + 1] : 0.f;
                        float t2 = (gk + 2 < N_) ? Az[gi * N_ + gk + 2] : 0.f;
                        float t3 = (gk + 3 < N_) ? Az[gi * N_ + gk + 3] : 0.f;
                        v = make_float4(t0, t1, t2, t3);
                    }
                }
                Ast[k + 0][i] = v.x; Ast[k + 1][i] = v.y;
                Ast[k + 2][i] = v.z; Ast[k + 3][i] = v.w;
            }
        }
        {
            #pragma unroll
            for (int q = 0; q < 2; ++q) {
                int id = tid + 256 * q;       // 0..511
                int k = id >> 4, jq = (id & 15) * 4;
                int gk = k0 + k, gj = j0 + jq;
                float4 v = make_float4(0.f, 0.f, 0.f, 0.f);
                if (gk < N_) {
                    if (gj + 3 < N_) v = *(const float4*)&Az[gk * N_ + gj];
                    else {
                        float t0 = (gj + 0 < N_) ? Az[gk * N_ + gj + 0] : 0.f;
                        float t1 = (gj + 1 < N_) ? Az[gk * N_ + gj + 1] : 0.f;
                        float t2 = (gj + 2 < N_) ? Az[gk * N_ + gj + 2] : 0.f;
                        float t3 = (gj + 3 < N_) ? Az[gk * N_ + gj + 3] : 0.f;
                        v = make_float4(t0, t1, t2, t3);
                    }
                }
                *(float4*)&Bs[k][jq] = v;
            }
        }
        __syncthreads();
        #pragma unroll 8
        for (int k = 0; k < 32; ++k) {
            float4 a0 = *(const float4*)&Ast[k][ty * 8];
            float4 a1 = *(const float4*)&Ast[k][ty * 8 + 4];
            float4 bv = *(const float4*)&Bs[k][tx * 4];
            acc[0][0] += a0.x * bv.x; acc[0][1] += a0.x * bv.y; acc[0][2] += a0.x * bv.z; acc[0][3] += a0.x * bv.w;
            acc[1][0] += a0.y * bv.x; acc[1][1] += a0.y * bv.y; acc[1][2] += a0.y * bv.z; acc[1][3] += a0.y * bv.w;
            acc[2][0] += a0.z * bv.x; acc[2][1] += a0.z * bv.y; acc[2][2] += a0.z * bv.z; acc[2][3] += a0.z * bv.w;
            acc[3][0] += a0.w * bv.x; acc[3][1] += a0.w * bv.y; acc[3][2] += a0.w * bv.z; acc[3][3] += a0.w * bv.w;
            acc[4][0] += a1.x * bv.x; acc[4][1] += a1.x * bv.y; acc[4][2] += a1.x * bv.z; acc[4][3] += a1.x * bv.w;
            acc[5][0] += a1.y * bv.x; acc[5][1] += a1.y * bv.y; acc[5][2] += a1.y * bv.z; acc[5][3] += a1.y * bv.w;
            acc[6][0] += a1.z * bv.x; acc[6][1] += a1.z * bv.y; acc[6][2] += a1.z * bv.z; acc[6][3] += a1.z * bv.w;
            acc[7][0] += a1.w * bv.x; acc[7][1] += a1.w * bv.y; acc[7][2] += a1.w * bv.z; acc[7][3] += a1.w * bv.w;
        }
        __syncthreads();
    }
    #pragma unroll
    for (int r = 0; r < 8; ++r) {
        int gi = i0 + ty * 8 + r;
        if (gi >= N_) continue;
        int gj = j0 + tx * 4;
        if (gj + 3 < N_) {
            *(float4*)&Cz[gi * N_ + gj] = make_float4(acc[r][0], acc[r][1], acc[r][2], acc[r][3]);
        } else {
            #pragma unroll
            for (int e = 0; e < 4; ++e) if (gj + e < N_) Cz[gi * N_ + gj + e] = acc[r][e];
        }
    }
}

// ======== xt-hops: xh[zl][i][4] = {A@x0, A@x1, A2@x0, A2@x1} ========
__global__ void __launch_bounds__(256) k_xh(
        const float* __restrict__ Abase, const float* __restrict__ A2base,
        const float* __restrict__ x, int z0, float* __restrict__ xh) {
    __shared__ float xtl[400];
    int zl = blockIdx.x, tid = threadIdx.x;
    int z = z0 + zl, t = z >> 3, b = z & 7;
    int w = tid >> 6, l = tid & 63;
    const float* xb = x + ((size_t)(b * T_ + t)) * N_ * 2;
    for (int idx = tid; idx < 400; idx += 256) xtl[idx] = xb[idx];
    __syncthreads();
    for (int it = 0; it < 50; ++it) {
        int i = it * 4 + w;
        float p0 = 0.f, p1 = 0.f, p2 = 0.f, p3 = 0.f;
        if (l < 50) {
            float4 a4 = *(const float4*)(Abase + (size_t)zl * NN_ + i * 200 + 4 * l);
            float4 c4 = *(const float4*)(A2base + (size_t)zl * NN_ + i * 200 + 4 * l);
            #pragma unroll
            for (int q = 0; q < 4; ++q) {
                float av = (&a4.x)[q], cv = (&c4.x)[q];
                float x0 = xtl[(4 * l + q) * 2], x1 = xtl[(4 * l + q) * 2 + 1];
                p0 += av * x0; p1 += av * x1; p2 += cv * x0; p3 += cv * x1;
            }
        }
        #pragma unroll
        for (int off = 32; off > 0; off >>= 1) {
            p0 += __shfl_down(p0, off); p1 += __shfl_down(p1, off);
            p2 += __shfl_down(p2, off); p3 += __shfl_down(p3, off);
        }
        if (l == 0) *(float4*)(xh + ((size_t)zl * N_ + i) * 4) = make_float4(p0, p1, p2, p3);
    }
}

// ======== K1: R11-proven wave-specialized (2 rows/block, 800 blocks) ========
__global__ void __launch_bounds__(256) k_ru2(
        const float* __restrict__ At, const float* __restrict__ A2t,
        const float* __restrict__ xht,
        const float* __restrict__ x, int t, const float* __restrict__ state,
        const float* __restrict__ Wru, const float* __restrict__ bru,
        float* __restrict__ rs, float* __restrict__ ub) {
    __shared__ float a2s[2 * 200], c2s[2 * 200];
    __shared__ float hpA[2][2][64], hpC[2][2][64];   // [h][r][c]
    __shared__ float feat[2][200];
    __shared__ float gp[12][2][128];                 // part1: 0..3, part2: 4..11
    int bx = blockIdx.x;
    int b = bx & 7, i0 = (bx >> 3) * 2;      // b == XCD -> state stays L2-local
    int tid = threadIdx.x;
    const float* F = state + (size_t)b * (N_ * 64);
    {   // stage: A/A2 rows, F->feat[.][2..65], x->[0..1], xh->[66..67],[132..133]
        const float4* Ar = (const float4*)(At + ((size_t)b * N_ + i0) * 200);
        const float4* Cr = (const float4*)(A2t + ((size_t)b * N_ + i0) * 200);
        if (tid < 100) { ((float4*)a2s)[tid] = Ar[tid]; ((float4*)c2s)[tid] = Cr[tid]; }
        if (tid >= 100 && tid < 164) {
            int l = tid - 100, r = l >> 5, q = l & 31;
            *(float2*)&feat[r][2 + 2 * q] = *(const float2*)&F[(size_t)(i0 + r) * 64 + 2 * q];
        }
        if (tid >= 164 && tid < 168) {
            int l = tid - 164;
            feat[l >> 1][l & 1] = x[((size_t)(b * T_ + t) * N_ + i0 + (l >> 1)) * 2 + (l & 1)];
        }
        if (tid >= 168 && tid < 176) {
            int l = tid - 168, rr = l >> 2, q = l & 3;
            feat[rr][(q < 2) ? (66 + q) : (132 + q - 2)] = xht[((size_t)b * N_ + i0 + rr) * 4 + q];
        }
    }
    __syncthreads();
    int w = tid >> 6, lane = tid & 63;
    if (w < 2) {   // hop: wave h = w owns j-half, computes BOTH rows
        int h = w;
        int cg = lane & 15, jq = lane >> 4;
        const float* a0p = a2s + h * 100;
        const float* a1p = a2s + 200 + h * 100;
        const float* c0p = c2s + h * 100;
        const float* c1p = c2s + 200 + h * 100;
        const float* Fb = F + (size_t)(h * 100) * 64 + 4 * cg;
        float4 aA0 = make_float4(0.f, 0.f, 0.f, 0.f), aA1 = aA0, aC0 = aA0, aC1 = aA0;
        #pragma unroll 5
        for (int m = 0; m < 25; ++m) {
            int j = jq + 4 * m;
            float4 f4 = *(const float4*)&Fb[(size_t)j * 64];
            float a0 = a0p[j], a1 = a1p[j], c0 = c0p[j], c1 = c1p[j];
            aA0.x += a0 * f4.x; aA0.y += a0 * f4.y; aA0.z += a0 * f4.z; aA0.w += a0 * f4.w;
            aA1.x += a1 * f4.x; aA1.y += a1 * f4.y; aA1.z += a1 * f4.z; aA1.w += a1 * f4.w;
            aC0.x += c0 * f4.x; aC0.y += c0 * f4.y; aC0.z += c0 * f4.z; aC0.w += c0 * f4.w;
            aC1.x += c1 * f4.x; aC1.y += c1 * f4.y; aC1.z += c1 * f4.z; aC1.w += c1 * f4.w;
        }
        #pragma unroll
        for (int off = 16; off <= 32; off <<= 1) {
            aA0.x += __shfl_xor(aA0.x, off); aA0.y += __shfl_xor(aA0.y, off);
            aA0.z += __shfl_xor(aA0.z, off); aA0.w += __shfl_xor(aA0.w, off);
            aA1.x += __shfl_xor(aA1.x, off); aA1.y += __shfl_xor(aA1.y, off);
            aA1.z += __shfl_xor(aA1.z, off); aA1.w += __shfl_xor(aA1.w, off);
            aC0.x += __shfl_xor(aC0.x, off); aC0.y += __shfl_xor(aC0.y, off);
            aC0.z += __shfl_xor(aC0.z, off); aC0.w += __shfl_xor(aC0.w, off);
            aC1.x += __shfl_xor(aC1.x, off); aC1.y += __shfl_xor(aC1.y, off);
            aC1.z += __shfl_xor(aC1.z, off); aC1.w += __shfl_xor(aC1.w, off);
        }
        if (lane < 16) {
            *(float4*)&hpA[h][0][4 * cg] = aA0;
            *(float4*)&hpA[h][1][4 * cg] = aA1;
            *(float4*)&hpC[h][0][4 * cg] = aC0;
            *(float4*)&hpC[h][1][4 * cg] = aC1;
        }
    } else {   // gate-part1: k in [0,68), features ready after stage
        int l = tid - 128;            // 0..127
        int cq = l & 31, kh = l >> 5; // kh 0..3
        int k0 = 17 * kh, kend = (k0 + 17 < 68) ? (k0 + 17) : 68;
        float4 s0 = make_float4(0.f, 0.f, 0.f, 0.f);
        float4 s1 = make_float4(0.f, 0.f, 0.f, 0.f);
        for (int k = k0; k < kend; ++k) {
            float4 w4 = *(const float4*)&Wru[(size_t)k * 128 + 4 * cq];
            float f0 = feat[0][k], f1 = feat[1][k];
            s0.x += f0 * w4.x; s0.y += f0 * w4.y; s0.z += f0 * w4.z; s0.w += f0 * w4.w;
            s1.x += f1 * w4.x; s1.y += f1 * w4.y; s1.z += f1 * w4.z; s1.w += f1 * w4.w;
        }
        *(float4*)&gp[kh][0][4 * cq] = s0;
        *(float4*)&gp[kh][1][4 * cq] = s1;
    }
    __syncthreads();
    {   // combine j-halves into feat[68..131], [134..197]
        int mt = tid >> 7, r = (tid >> 6) & 1, c = tid & 63;
        float v = mt ? (hpC[0][r][c] + hpC[1][r][c]) : (hpA[0][r][c] + hpA[1][r][c]);
        feat[r][(mt ? 134 : 68) + c] = v;
    }
    __syncthreads();
    {   // gate-part2: k in [68,198), 8 splits of 17 (last 11)
        int cq = tid & 31, kh = tid >> 5;
        int k0 = 68 + 17 * kh, kend = (k0 + 17 < 198) ? (k0 + 17) : 198;
        float4 s0 = make_float4(0.f, 0.f, 0.f, 0.f);
        float4 s1 = make_float4(0.f, 0.f, 0.f, 0.f);
        for (int k = k0; k < kend; ++k) {
            float4 w4 = *(const float4*)&Wru[(size_t)k * 128 + 4 * cq];
            float f0 = feat[0][k], f1 = feat[1][k];
            s0.x += f0 * w4.x; s0.y += f0 * w4.y; s0.z += f0 * w4.z; s0.w += f0 * w4.w;
            s1.x += f1 * w4.x; s1.y += f1 * w4.y; s1.z += f1 * w4.z; s1.w += f1 * w4.w;
        }
        *(float4*)&gp[4 + kh][0][4 * cq] = s0;
        *(float4*)&gp[4 + kh][1][4 * cq] = s1;
    }
    __syncthreads();
    {   // reduce + activation + store
        int rq = tid >> 7, c = tid & 127;
        float a = bru[c];
        #pragma unroll
        for (int h = 0; h < 12; ++h) a += gp[h][rq][c];
        float v = sigm(a);
        size_t go = (size_t)b * N_ + i0 + rq;
        if (c < 64) rs[go * 64 + c] = v * feat[rq][2 + c];
        else        ub[go * 64 + (c - 64)] = v;
    }
}

// ======== K2: R11-proven wave-specialized, 64-col gate ========
__global__ void __launch_bounds__(256) k_cand2(
        const float* __restrict__ At, const float* __restrict__ A2t,
        const float* __restrict__ xht,
        const float* __restrict__ x, int t, const float* __restrict__ rsin,
        const float* __restrict__ Wcd, const float* __restrict__ bcd,
        const float* __restrict__ ub, float* __restrict__ state) {
    __shared__ float a2s[2 * 200], c2s[2 * 200];
    __shared__ float hpA[2][2][64], hpC[2][2][64];
    __shared__ float feat[2][200];
    __shared__ float gp[24][2][64];                  // part1: 0..7, part2: 8..23
    int bx = blockIdx.x;
    int b = bx & 7, i0 = (bx >> 3) * 2;
    int tid = threadIdx.x;
    const float* F = rsin + (size_t)b * (N_ * 64);
    {
        const float4* Ar = (const float4*)(At + ((size_t)b * N_ + i0) * 200);
        const float4* Cr = (const float4*)(A2t + ((size_t)b * N_ + i0) * 200);
        if (tid < 100) { ((float4*)a2s)[tid] = Ar[tid]; ((float4*)c2s)[tid] = Cr[tid]; }
        if (tid >= 100 && tid < 164) {
            int l = tid - 100, r = l >> 5, q = l & 31;
            *(float2*)&feat[r][2 + 2 * q] = *(const float2*)&F[(size_t)(i0 + r) * 64 + 2 * q];
        }
        if (tid >= 164 && tid < 168) {
            int l = tid - 164;
            feat[l >> 1][l & 1] = x[((size_t)(b * T_ + t) * N_ + i0 + (l >> 1)) * 2 + (l & 1)];
        }
        if (tid >= 168 && tid < 176) {
            int l = tid - 168, rr = l >> 2, q = l & 3;
            feat[rr][(q < 2) ? (66 + q) : (132 + q - 2)] = xht[((size_t)b * N_ + i0 + rr) * 4 + q];
        }
    }
    __syncthreads();
    int w = tid >> 6, lane = tid & 63;
    if (w < 2) {   // hop over rs, 1 F load -> both rows
        int h = w;
        int cg = lane & 15, jq = lane >> 4;
        const float* a0p = a2s + h * 100;
        const float* a1p = a2s + 200 + h * 100;
        const float* c0p = c2s + h * 100;
        const float* c1p = c2s + 200 + h * 100;
        const float* Fb = F + (size_t)(h * 100) * 64 + 4 * cg;
        float4 aA0 = make_float4(0.f, 0.f, 0.f, 0.f), aA1 = aA0, aC0 = aA0, aC1 = aA0;
        #pragma unroll 5
        for (int m = 0; m < 25; ++m) {
            int j = jq + 4 * m;
            float4 f4 = *(const float4*)&Fb[(size_t)j * 64];
            float a0 = a0p[j], a1 = a1p[j], c0 = c0p[j], c1 = c1p[j];
            aA0.x += a0 * f4.x; aA0.y += a0 * f4.y; aA0.z += a0 * f4.z; aA0.w += a0 * f4.w;
            aA1.x += a1 * f4.x; aA1.y += a1 * f4.y; aA1.z += a1 * f4.z; aA1.w += a1 * f4.w;
            aC0.x += c0 * f4.x; aC0.y += c0 * f4.y; aC0.z += c0 * f4.z; aC0.w += c0 * f4.w;
            aC1.x += c1 * f4.x; aC1.y += c1 * f4.y; aC1.z += c1 * f4.z; aC1.w += c1 * f4.w;
        }
        #pragma unroll
        for (int off = 16; off <= 32; off <<= 1) {
            aA0.x += __shfl_xor(aA0.x, off); aA0.y += __shfl_xor(aA0.y, off);
            aA0.z += __shfl_xor(aA0.z, off); aA0.w += __shfl_xor(aA0.w, off);
            aA1.x += __shfl_xor(aA1.x, off); aA1.y += __shfl_xor(aA1.y, off);
            aA1.z += __shfl_xor(aA1.z, off); aA1.w += __shfl_xor(aA1.w, off);
            aC0.x += __shfl_xor(aC0.x, off); aC0.y += __shfl_xor(aC0.y, off);
            aC0.z += __shfl_xor(aC0.z, off); aC0.w += __shfl_xor(aC0.w, off);
            aC1.x += __shfl_xor(aC1.x, off); aC1.y += __shfl_xor(aC1.y, off);
            aC1.z += __shfl_xor(aC1.z, off); aC1.w += __shfl_xor(aC1.w, off);
        }
        if (lane < 16) {
            *(float4*)&hpA[h][0][4 * cg] = aA0;
            *(float4*)&hpA[h][1][4 * cg] = aA1;
            *(float4*)&hpC[h][0][4 * cg] = aC0;
            *(float4*)&hpC[h][1][4 * cg] = aC1;
        }
    } else {   // gate-part1: k in [0,68)
        int l = tid - 128;            // 0..127
        int cq = l & 15, kh = l >> 4; // kh 0..7
        int k0 = 9 * kh, kend = (k0 + 9 < 68) ? (k0 + 9) : 68;
        float4 s0 = make_float4(0.f, 0.f, 0.f, 0.f);
        float4 s1 = make_float4(0.f, 0.f, 0.f, 0.f);
        for (int k = k0; k < kend; ++k) {
            float4 w4 = *(const float4*)&Wcd[(size_t)k * 64 + 4 * cq];
            float f0 = feat[0][k], f1 = feat[1][k];
            s0.x += f0 * w4.x; s0.y += f0 * w4.y; s0.z += f0 * w4.z; s0.w += f0 * w4.w;
            s1.x += f1 * w4.x; s1.y += f1 * w4.y; s1.z += f1 * w4.z; s1.w += f1 * w4.w;
        }
        *(float4*)&gp[kh][0][4 * cq] = s0;
        *(float4*)&gp[kh][1][4 * cq] = s1;
    }
    __syncthreads();
    {
        int mt = tid >> 7, r = (tid >> 6) & 1, c = tid & 63;
        float v = mt ? (hpC[0][r][c] + hpC[1][r][c]) : (hpA[0][r][c] + hpA[1][r][c]);
        feat[r][(mt ? 134 : 68) + c] = v;
    }
    __syncthreads();
    {   // gate-part2: k in [68,198), 16 splits of 9
        int cq = tid & 15, kh = tid >> 4;
        int k0 = 68 + 9 * kh;
        int kend = (k0 + 9 < 198) ? (k0 + 9) : 198;
        float4 s0 = make_float4(0.f, 0.f, 0.f, 0.f);
        float4 s1 = make_float4(0.f, 0.f, 0.f, 0.f);
        for (int k = k0; k < kend; ++k) {
            float4 w4 = *(const float4*)&Wcd[(size_t)k * 64 + 4 * cq];
            float f0 = feat[0][k], f1 = feat[1][k];
            s0.x += f0 * w4.x; s0.y += f0 * w4.y; s0.z += f0 * w4.z; s0.w += f0 * w4.w;
            s1.x += f1 * w4.x; s1.y += f1 * w4.y; s1.z += f1 * w4.z; s1.w += f1 * w4.w;
        }
        *(float4*)&gp[8 + kh][0][4 * cq] = s0;
        *(float4*)&gp[8 + kh][1][4 * cq] = s1;
    }
    __syncthreads();
    if (tid < 128) {
        int rq = tid >> 6, c = tid & 63;
        float a = bcd[c];
        #pragma unroll
        for (int h = 0; h < 24; ++h) a += gp[h][rq][c];
        size_t go = (size_t)b * N_ + i0 + rq;
        float cnd = tanhf(a);
        float u = ub[go * 64 + c];
        float st = state[go * 64 + c];
        state[go * 64 + c] = u * st + (1.f - u) * cnd;
    }
}

// ======== pred head ========
__global__ void __launch_bounds__(64) k_pred(
        const float* __restrict__ state,
        const float* __restrict__ Wp1, const float* __restrict__ bp1,
        const float* __restrict__ Wp2, const float* __restrict__ bp2,
        float* __restrict__ out) {
    __shared__ float st[64];
    int row = blockIdx.x;
    int tid = threadIdx.x;
    st[tid] = state[row * 64 + tid];
    __syncthreads();
    float acc = bp1[tid];
    #pragma unroll 8
    for (int a = 0; a < 64; ++a) acc += st[a] * Wp1[a * 64 + tid];
    acc = acc > 0.f ? acc : 0.01f * acc;
    float v = acc * Wp2[tid];
    #pragma unroll
    for (int off = 32; off > 0; off >>= 1) v += __shfl_down(v, off);
    if (tid == 0) out[row] = v + bp2[0];
}

extern "C" void kernel_launch(void* const* d_in, const int* in_sizes, int n_in,
                              void* d_out, int out_size, void* d_ws, size_t ws_size,
                              hipStream_t stream) {
    const float* x    = (const float*)d_in[0];
    const float* nf   = (const float*)d_in[1];
    const float* Ws2d = (const float*)d_in[2];
    const float* bs2d = (const float*)d_in[3];
    const float* Wrz  = (const float*)d_in[4];
    const float* brz  = (const float*)d_in[5];
    const float* Wh   = (const float*)d_in[6];
    const float* bh   = (const float*)d_in[7];
    const float* Wc2  = (const float*)d_in[8];
    const float* bc2  = (const float*)d_in[9];
    const float* Wc1  = (const float*)d_in[10];
    const float* bc1  = (const float*)d_in[11];
    const float* Wm2  = (const float*)d_in[12];
    const float* bm2  = (const float*)d_in[13];
    const float* Wm1  = (const float*)d_in[14];
    const float* bm1  = (const float*)d_in[15];
    const float* Wru  = (const float*)d_in[16];
    const float* bru  = (const float*)d_in[17];
    const float* Wcand= (const float*)d_in[18];
    const float* bcand= (const float*)d_in[19];
    const float* Wp1  = (const float*)d_in[20];
    const float* bp1  = (const float*)d_in[21];
    const float* Wp2  = (const float*)d_in[22];
    const float* bp2  = (const float*)d_in[23];
    float* out = (float*)d_out;

    float* ws = (float*)d_ws;
    const size_t PQ = (size_t)T_ * R_ * 32;
    float* Pc = ws;
    float* Qc = Pc + PQ;
    float* Pm = Qc + PQ;
    float* Qm = Pm + PQ;

    const size_t A2F = (size_t)96 * NN_;
    const size_t XHF = (size_t)96 * N_ * 4;
    const size_t FULL_NEED = (A2F + XHF + 3 * (size_t)R_ * 64) * 4;
    bool full = ws_size >= FULL_NEED;

    const float* Aall = out + R_;

    if (full) {
        float* A2base = ws;                  // aliases dead P/Q after k_pairall
        float* xhbase = ws + A2F;
        float* state  = xhbase + XHF;
        float* rs     = state + (size_t)R_ * 64;
        float* ub     = rs + (size_t)R_ * 64;

        k_dyall<<<400, 256, 0, stream>>>(x, nf, Ws2d, bs2d, Wrz, brz, Wh, bh,
                                         Wc2, Wm2, bc2, bm2, Pc, Qc, Pm, Qm, state);
        k_pairall<<<dim3(13, 13, 96), dim3(16, 16), 0, stream>>>(
            Pc, Qc, Pm, Qm, Wc1, bc1, Wm1, bm1, out);
        k_a2<<<96 * 8, 256, 0, stream>>>(Aall, A2base, 96);
        k_xh<<<96, 256, 0, stream>>>(Aall, A2base, x, 0, xhbase);

        for (int t = 0; t < T_; ++t) {
            const float* At  = Aall + (size_t)t * 8 * NN_;
            const float* A2t = A2base + (size_t)t * 8 * NN_;
            const float* xht = xhbase + (size_t)t * 8 * N_ * 4;
            k_ru2  <<<800, 256, 0, stream>>>(At, A2t, xht, x, t, state, Wru, bru, rs, ub);
            k_cand2<<<800, 256, 0, stream>>>(At, A2t, xht, x, t, rs, Wcand, bcand, ub, state);
        }
        k_pred<<<R_, 64, 0, stream>>>(state, Wp1, bp1, Wp2, bp2, out);
    } else {
        float* A2base = ws + 4 * PQ;
        float* xhbase = A2base + (size_t)8 * NN_;
        float* state  = xhbase + (size_t)8 * N_ * 4;
        float* rs     = state + (size_t)R_ * 64;
        float* ub     = rs + (size_t)R_ * 64;

        k_dyall<<<400, 256, 0, stream>>>(x, nf, Ws2d, bs2d, Wrz, brz, Wh, bh,
                                         Wc2, Wm2, bc2, bm2, Pc, Qc, Pm, Qm, state);
        k_pairall<<<dim3(13, 13, 96), dim3(16, 16), 0, stream>>>(
            Pc, Qc, Pm, Qm, Wc1, bc1, Wm1, bm1, out);
        for (int t = 0; t < T_; ++t) {
            const float* At = Aall + (size_t)t * 8 * NN_;
            k_a2<<<8 * 8, 256, 0, stream>>>(At, A2base, 8);
            k_xh<<<8, 256, 0, stream>>>(At, A2base, x, t * 8, xhbase);
            k_ru2  <<<800, 256, 0, stream>>>(At, A2base, xhbase, x, t, state, Wru, bru, rs, ub);
            k_cand2<<<800, 256, 0, stream>>>(At, A2base, xhbase, x, t, rs, Wcand, bcand, ub, state);
        }
        k_pred<<<R_, 64, 0, stream>>>(state, Wp1, bp1, Wp2, bp2, out);
    }
}